// Round 2
// baseline (591.970 us; speedup 1.0000x reference)
//
#include <hip/hip_runtime.h>
#include <math.h>

// Problem constants (b=2, cin=256, h=w=64, C=64, qc=60, pd=4, OUT_K=7)
#define HWN 4096
#define CIN 256
#define CCH 64
#define QC  60
#define RAD 3
#define NTAP 49
#define HH 64
#define WW 64

// ---------------- K0: transpose Wout (o,c,k,l) -> Wt (o, kl, c) ----------------
__global__ __launch_bounds__(256) void k_twout(const float* __restrict__ Wout,
                                               float* __restrict__ Wt) {
    int idx = blockIdx.x * 256 + threadIdx.x;
    if (idx >= 64 * 64 * 49) return;
    int o   = idx / (64 * 49);
    int rem = idx - o * (64 * 49);
    int c   = rem / 49;
    int kl  = rem - c * 49;
    Wt[o * 3136 + kl * 64 + c] = Wout[idx];
}

// ---------------- K1: QKV projection + positional channels ----------------
// Q,K,V layout: [b][n][c], c contiguous (64 channels: 0..59 proj, 60..63 pos)
__global__ __launch_bounds__(256) void k_qkv(
    const float* __restrict__ x,
    const float* __restrict__ Wq, const float* __restrict__ bq,
    const float* __restrict__ Wk, const float* __restrict__ bk,
    const float* __restrict__ Wv, const float* __restrict__ bv,
    const float* __restrict__ Wp, const float* __restrict__ bp,
    float* __restrict__ Q, float* __restrict__ K, float* __restrict__ V)
{
    __shared__ float xl[CIN * 64];     // [c][pix] 64 KB
    int b  = blockIdx.x >> 6;          // 2 batches x 64 pixel-tiles
    int n0 = (blockIdx.x & 63) * 64;
    int t  = threadIdx.x;
    const float* xb = x + (size_t)b * CIN * HWN + n0;
    for (int idx = t; idx < CIN * 64; idx += 256) {
        int c = idx >> 6, p = idx & 63;
        xl[idx] = xb[c * HWN + p];
    }
    __syncthreads();
    int pix = t & 63, g = t >> 6;      // g in 0..3
    int gn  = b * HWN + n0 + pix;
    // 180 projection channels (60 q | 60 k | 60 v), 45 per thread-group
    for (int s = 0; s < 45; ++s) {
        int ch = g * 45 + s;
        int which = ch / 60;
        int o     = ch - which * 60;
        const float* Wm = (which == 0) ? Wq : (which == 1) ? Wk : Wv;
        const float* bm = (which == 0) ? bq : (which == 1) ? bk : bv;
        const float* wr = Wm + o * CIN;
        float acc = bm[o];
        #pragma unroll 8
        for (int c = 0; c < CIN; ++c) acc = fmaf(xl[c * 64 + pix], wr[c], acc);
        float* outb = (which == 0) ? Q : (which == 1) ? K : V;
        outb[(size_t)gn * CCH + o] = acc;
    }
    // positional channels 60..63 (identical in Q, K, V)
    {
        int po = g;
        int n  = n0 + pix;
        float fi = (float)(n >> 6), fj = (float)(n & 63);
        float pv = fmaf(Wp[po * 2], fi, fmaf(Wp[po * 2 + 1], fj, bp[po]));
        Q[(size_t)gn * CCH + QC + po] = pv;
        K[(size_t)gn * CCH + QC + po] = pv;
        V[(size_t)gn * CCH + QC + po] = pv;
    }
}

// ---------------- K2: flash-style row stats (max M, sum L of exp(qk)) ----------------
// block = 32 query rows, streams all 64-col tiles. threads 16x16, micro 2x4.
__global__ __launch_bounds__(256) void k_stats(
    const float* __restrict__ Q, const float* __restrict__ Kb,
    float* __restrict__ Mo, float* __restrict__ Lo)
{
    const int STRQ = 36;                // 32-wide arrays (+4 pad)
    const int STRK = 68;                // 64-wide arrays (+4 pad, 16B-aligned)
    __shared__ float Qt[64 * STRQ];     // [c][row 0..31]
    __shared__ float Kt[64 * STRK];     // [c][col 0..63]
    int b  = blockIdx.x >> 7;           // 2 x 128 row-tiles
    int n0 = (blockIdx.x & 127) * 32;
    int t  = threadIdx.x;
    int tx = t & 15, ty = t >> 4;
    int r0 = ty * 2, c0 = tx * 4;

    const float* Qrow = Q + ((size_t)b * HWN + n0) * CCH;
    for (int idx = t; idx < 32 * 64; idx += 256) {
        int r = idx >> 6, c = idx & 63;
        Qt[c * STRQ + r] = Qrow[r * CCH + c];
    }

    float m0 = -1e30f, m1 = -1e30f, l0 = 0.f, l1 = 0.f;

    for (int ct = 0; ct < HWN; ct += 64) {
        __syncthreads();
        const float* Krow = Kb + ((size_t)b * HWN + ct) * CCH;
        for (int idx = t; idx < 64 * 64; idx += 256) {
            int r = idx >> 6, c = idx & 63;
            Kt[c * STRK + r] = Krow[r * CCH + c];
        }
        __syncthreads();

        float a00=0,a01=0,a02=0,a03=0,a10=0,a11=0,a12=0,a13=0;
        #pragma unroll 8
        for (int c = 0; c < 64; ++c) {
            float q0 = Qt[c * STRQ + r0];
            float q1 = Qt[c * STRQ + r0 + 1];
            const float4 k4 = *(const float4*)(&Kt[c * STRK + c0]);
            a00 = fmaf(q0, k4.x, a00); a01 = fmaf(q0, k4.y, a01);
            a02 = fmaf(q0, k4.z, a02); a03 = fmaf(q0, k4.w, a03);
            a10 = fmaf(q1, k4.x, a10); a11 = fmaf(q1, k4.y, a11);
            a12 = fmaf(q1, k4.z, a12); a13 = fmaf(q1, k4.w, a13);
        }
        // scale, diag-zero, online (m,l) update — row 0
        {
            int gr = n0 + r0;
            float v0 = (gr == ct + c0 + 0) ? 0.f : a00 * 0.125f;
            float v1 = (gr == ct + c0 + 1) ? 0.f : a01 * 0.125f;
            float v2 = (gr == ct + c0 + 2) ? 0.f : a02 * 0.125f;
            float v3 = (gr == ct + c0 + 3) ? 0.f : a03 * 0.125f;
            float tm = fmaxf(fmaxf(v0, v1), fmaxf(v2, v3));
            if (tm > m0) { l0 *= __expf(m0 - tm); m0 = tm; }
            l0 += __expf(v0 - m0) + __expf(v1 - m0) + __expf(v2 - m0) + __expf(v3 - m0);
        }
        // row 1
        {
            int gr = n0 + r0 + 1;
            float v0 = (gr == ct + c0 + 0) ? 0.f : a10 * 0.125f;
            float v1 = (gr == ct + c0 + 1) ? 0.f : a11 * 0.125f;
            float v2 = (gr == ct + c0 + 2) ? 0.f : a12 * 0.125f;
            float v3 = (gr == ct + c0 + 3) ? 0.f : a13 * 0.125f;
            float tm = fmaxf(fmaxf(v0, v1), fmaxf(v2, v3));
            if (tm > m1) { l1 *= __expf(m1 - tm); m1 = tm; }
            l1 += __expf(v0 - m1) + __expf(v1 - m1) + __expf(v2 - m1) + __expf(v3 - m1);
        }
    }

    // merge (m,l) across the 16 tx-lanes sharing each row pair
    #pragma unroll
    for (int off = 1; off < 16; off <<= 1) {
        float m2 = __shfl_xor(m0, off, 64);
        float l2 = __shfl_xor(l0, off, 64);
        float M2 = fmaxf(m0, m2);
        l0 = l0 * __expf(m0 - M2) + l2 * __expf(m2 - M2);
        m0 = M2;
        m2 = __shfl_xor(m1, off, 64);
        l2 = __shfl_xor(l1, off, 64);
        M2 = fmaxf(m1, m2);
        l1 = l1 * __expf(m1 - M2) + l2 * __expf(m2 - M2);
        m1 = M2;
    }
    if (tx == 0) {
        Mo[b * HWN + n0 + r0]     = m0;
        Lo[b * HWN + n0 + r0]     = l0;
        Mo[b * HWN + n0 + r0 + 1] = m1;
        Lo[b * HWN + n0 + r0 + 1] = l1;
    }
}

// ---------------- K2.5: local attention weights (recompute 49 dots per pixel) ----------------
__global__ __launch_bounds__(64) void k_attn(
    const float* __restrict__ Q, const float* __restrict__ Kb,
    const float* __restrict__ Mo, const float* __restrict__ Lo,
    float* __restrict__ A)
{
    int gid = blockIdx.x;               // b*4096 + n
    int b = gid >> 12, n = gid & 4095;
    int t = threadIdx.x;
    if (t >= NTAP) return;
    int i = n >> 6, j = n & 63;
    float Mv = Mo[gid], Lv = Lo[gid];
    int k  = t / 7, lx = t - k * 7;
    int hi = min(max(i + k - RAD, 0), HH - 1);
    int wi = min(max(j + lx - RAD, 0), WW - 1);
    int src = hi * WW + wi;
    const float* qr = Q + ((size_t)b * HWN + n) * CCH;
    const float* kr = Kb + ((size_t)b * HWN + src) * CCH;
    float acc = 0.f;
    #pragma unroll 8
    for (int c = 0; c < CCH; ++c) acc = fmaf(qr[c], kr[c], acc);
    float val = (src == n) ? 0.f : acc * 0.125f;
    A[(size_t)gid * NTAP + t] = __expf(val - Mv) / Lv;
}

// ---------------- K3: output GEMM  out[q,o] = sum_{kl,c} (attn*Vloc) * Wt ----------------
// block = 32 query pixels x 64 out channels; loops over the 49 taps.
__global__ __launch_bounds__(256) void k_out(
    const float* __restrict__ A, const float* __restrict__ V,
    const float* __restrict__ Wt, const float* __restrict__ bout,
    float* __restrict__ out)
{
    const int STRQ = 36;                // 32-wide (+4 pad)
    const int STRK = 68;                // 64-wide (+4 pad)
    __shared__ float Rt[64 * STRQ];     // [c][q 0..31]  (attn-scaled V rows)
    __shared__ float Wl[64 * STRK];     // [c][o 0..63]
    __shared__ float Al[32][NTAP];
    int b  = blockIdx.x >> 7;
    int n0 = (blockIdx.x & 127) * 32;
    int t  = threadIdx.x;
    int tx = t & 15, ty = t >> 4;
    int r0 = ty * 2, c0 = tx * 4;

    for (int idx = t; idx < 32 * NTAP; idx += 256) {
        int q = idx / NTAP, kl = idx - q * NTAP;
        Al[q][kl] = A[((size_t)b * HWN + n0 + q) * NTAP + kl];
    }

    float a00=0,a01=0,a02=0,a03=0,a10=0,a11=0,a12=0,a13=0;

    for (int kl = 0; kl < NTAP; ++kl) {
        __syncthreads();
        int k = kl / 7, lx = kl - k * 7;
        for (int idx = t; idx < 64 * 64; idx += 256) {
            int o = idx >> 6, c = idx & 63;
            Wl[c * STRK + o] = Wt[o * 3136 + kl * 64 + c];
        }
        for (int idx = t; idx < 32 * 64; idx += 256) {
            int q = idx >> 6, c = idx & 63;
            int n = n0 + q;
            int i = n >> 6, j = n & 63;
            int hi = min(max(i + k - RAD, 0), HH - 1);
            int wi = min(max(j + lx - RAD, 0), WW - 1);
            int src = hi * WW + wi;
            Rt[c * STRQ + q] = Al[q][kl] * V[((size_t)b * HWN + src) * CCH + c];
        }
        __syncthreads();
        #pragma unroll 8
        for (int c = 0; c < 64; ++c) {
            float q0 = Rt[c * STRQ + r0];
            float q1 = Rt[c * STRQ + r0 + 1];
            const float4 w4 = *(const float4*)(&Wl[c * STRK + c0]);
            a00 = fmaf(q0, w4.x, a00); a01 = fmaf(q0, w4.y, a01);
            a02 = fmaf(q0, w4.z, a02); a03 = fmaf(q0, w4.w, a03);
            a10 = fmaf(q1, w4.x, a10); a11 = fmaf(q1, w4.y, a11);
            a12 = fmaf(q1, w4.z, a12); a13 = fmaf(q1, w4.w, a13);
        }
    }

    // epilogue: bias + relu, write out[b][o][n]
    float acc[2][4] = {{a00,a01,a02,a03},{a10,a11,a12,a13}};
    #pragma unroll
    for (int i2 = 0; i2 < 2; ++i2)
        #pragma unroll
        for (int j2 = 0; j2 < 4; ++j2) {
            int o = c0 + j2, n = n0 + r0 + i2;
            float v = fmaxf(acc[i2][j2] + bout[o], 0.f);
            out[((size_t)(b * CCH + o)) * HWN + n] = v;
        }
}

// ---------------- launch ----------------
extern "C" void kernel_launch(void* const* d_in, const int* in_sizes, int n_in,
                              void* d_out, int out_size, void* d_ws, size_t ws_size,
                              hipStream_t stream) {
    const float* x    = (const float*)d_in[0];
    const float* Wq   = (const float*)d_in[1];
    const float* bq   = (const float*)d_in[2];
    const float* Wk   = (const float*)d_in[3];
    const float* bk   = (const float*)d_in[4];
    const float* Wv   = (const float*)d_in[5];
    const float* bv   = (const float*)d_in[6];
    const float* Wp   = (const float*)d_in[7];
    const float* bp   = (const float*)d_in[8];
    const float* Wout = (const float*)d_in[9];
    const float* bout = (const float*)d_in[10];
    float* out = (float*)d_out;

    // ws layout (floats): Wt | Q | K | V | M | L | A   (~8.8 MB total)
    float* ws = (float*)d_ws;
    float* Wt = ws;                   // 200704
    float* Qb = Wt + 200704;          // 524288
    float* Kb = Qb + 524288;          // 524288
    float* Vb = Kb + 524288;          // 524288
    float* Mo = Vb + 524288;          // 8192
    float* Lo = Mo + 8192;            // 8192
    float* A  = Lo + 8192;            // 401408

    hipLaunchKernelGGL(k_twout, dim3(784),  dim3(256), 0, stream, Wout, Wt);
    hipLaunchKernelGGL(k_qkv,   dim3(128),  dim3(256), 0, stream,
                       x, Wq, bq, Wk, bk, Wv, bv, Wp, bp, Qb, Kb, Vb);
    hipLaunchKernelGGL(k_stats, dim3(256),  dim3(256), 0, stream, Qb, Kb, Mo, Lo);
    hipLaunchKernelGGL(k_attn,  dim3(8192), dim3(64),  0, stream, Qb, Kb, Mo, Lo, A);
    hipLaunchKernelGGL(k_out,   dim3(256),  dim3(256), 0, stream, A, Vb, Wt, bout, out);
}

// Round 3
// 319.601 us; speedup vs baseline: 1.8522x; 1.8522x over previous
//
#include <hip/hip_runtime.h>
#include <math.h>

// Problem constants (b=2, cin=256, h=w=64, C=64, qc=60, pd=4, OUT_K=7)
#define HWN 4096
#define CIN 256
#define CCH 64
#define QC  60
#define RAD 3
#define NTAP 49

// ws layout (float offsets)
#define WT0  0
#define QB0  200704
#define KB0  724992
#define VB0  1249280
#define LP0  1773568          // 4 splits x 2 b x 4096
#define A0   1806336          // 2 x 4096 x 49
#define ST0  2207744          // 4 ints: q2max[2], k2max[2]

// ---------------- K0: transpose Wout (o,c,k,l) -> Wt (o, kl, c) ----------------
__global__ __launch_bounds__(256) void k_twout(const float* __restrict__ Wout,
                                               float* __restrict__ Wt) {
    int idx = blockIdx.x * 256 + threadIdx.x;
    if (idx >= 64 * 64 * 49) return;
    int o   = idx / (64 * 49);
    int rem = idx - o * (64 * 49);
    int c   = rem / 49;
    int kl  = rem - c * 49;
    Wt[o * 3136 + kl * 64 + c] = Wout[idx];
}

// ---------------- K0b: positional channels 60..63 of Q,K,V ----------------
__global__ __launch_bounds__(256) void k_pos(
    const float* __restrict__ Wp, const float* __restrict__ bp,
    float* __restrict__ Q, float* __restrict__ K, float* __restrict__ V)
{
    int idx = blockIdx.x * 256 + threadIdx.x;   // 8192 = b*4096+n
    int n = idx & 4095;
    float fi = (float)(n >> 6), fj = (float)(n & 63);
    float4 pv;
    pv.x = fmaf(Wp[0], fi, fmaf(Wp[1], fj, bp[0]));
    pv.y = fmaf(Wp[2], fi, fmaf(Wp[3], fj, bp[1]));
    pv.z = fmaf(Wp[4], fi, fmaf(Wp[5], fj, bp[2]));
    pv.w = fmaf(Wp[6], fi, fmaf(Wp[7], fj, bp[3]));
    size_t base = (size_t)idx * CCH + QC;
    *(float4*)(Q + base) = pv;
    *(float4*)(K + base) = pv;
    *(float4*)(V + base) = pv;
}

// ---------------- K1: QKV projection GEMM (ch 0..59) ----------------
// grid 768 = 2b x 128 pixel-tiles(32) x 3 mats. 256 thr, micro 2pix x 4ch.
__global__ __launch_bounds__(256) void k_qkv(
    const float* __restrict__ x,
    const float* __restrict__ Wq, const float* __restrict__ bq,
    const float* __restrict__ Wk, const float* __restrict__ bk,
    const float* __restrict__ Wv, const float* __restrict__ bv,
    float* __restrict__ Q, float* __restrict__ K, float* __restrict__ V)
{
    __shared__ float Xs[64][33];   // [k][pix]
    __shared__ float Ws[64][65];   // [och][k]
    int gid  = blockIdx.x;
    int mat  = gid % 3;
    int rest = gid / 3;
    int b    = rest >> 7;
    int n0   = (rest & 127) * 32;
    const float* Wm = (mat == 0) ? Wq : (mat == 1) ? Wk : Wv;
    const float* bm = (mat == 0) ? bq : (mat == 1) ? bk : bv;
    float*       Ob = (mat == 0) ? Q  : (mat == 1) ? K  : V;

    int t  = threadIdx.x;
    int tx = t & 15, ty = t >> 4;       // och0 = 4tx, pix0 = 2ty
    float f00=0,f01=0,f02=0,f03=0,f10=0,f11=0,f12=0,f13=0;

    for (int c0 = 0; c0 < CIN; c0 += 64) {
        __syncthreads();
        for (int idx = t; idx < 64 * 32; idx += 256) {
            int k = idx >> 5, p = idx & 31;
            Xs[k][p] = x[((size_t)(b * CIN + c0 + k) << 12) + n0 + p];
        }
        for (int idx = t; idx < 64 * 64; idx += 256) {
            int o = idx >> 6, k = idx & 63;
            Ws[o][k] = (o < QC) ? Wm[o * CIN + c0 + k] : 0.f;
        }
        __syncthreads();
        #pragma unroll 4
        for (int k = 0; k < 64; ++k) {
            float x0 = Xs[k][2 * ty];
            float x1 = Xs[k][2 * ty + 1];
            float w0 = Ws[4 * tx + 0][k];
            float w1 = Ws[4 * tx + 1][k];
            float w2 = Ws[4 * tx + 2][k];
            float w3 = Ws[4 * tx + 3][k];
            f00 = fmaf(x0, w0, f00); f01 = fmaf(x0, w1, f01);
            f02 = fmaf(x0, w2, f02); f03 = fmaf(x0, w3, f03);
            f10 = fmaf(x1, w0, f10); f11 = fmaf(x1, w1, f11);
            f12 = fmaf(x1, w2, f12); f13 = fmaf(x1, w3, f13);
        }
    }
    if (tx < 15) {                       // och 60..63 are pos channels
        float4 bb = *(const float4*)(bm + 4 * tx);
        float4 v0 = make_float4(f00 + bb.x, f01 + bb.y, f02 + bb.z, f03 + bb.w);
        float4 v1 = make_float4(f10 + bb.x, f11 + bb.y, f12 + bb.z, f13 + bb.w);
        size_t base = ((size_t)(b << 12) + n0 + 2 * ty) * CCH + 4 * tx;
        *(float4*)(Ob + base)       = v0;
        *(float4*)(Ob + base + CCH) = v1;
    }
}

// ---------------- K1b: row norms -> per-batch max |q|^2, |k|^2 ----------------
__global__ __launch_bounds__(256) void k_norm(
    const float* __restrict__ Q, const float* __restrict__ K, int* __restrict__ ST)
{
    int idx = blockIdx.x * 256 + threadIdx.x;   // 8192
    int b = idx >> 12;
    const float4* q4 = (const float4*)(Q + (size_t)idx * CCH);
    const float4* k4 = (const float4*)(K + (size_t)idx * CCH);
    float q2 = 0.f, k2 = 0.f;
    #pragma unroll
    for (int c = 0; c < 16; ++c) {
        float4 a = q4[c], d = k4[c];
        q2 = fmaf(a.x,a.x, fmaf(a.y,a.y, fmaf(a.z,a.z, fmaf(a.w,a.w, q2))));
        k2 = fmaf(d.x,d.x, fmaf(d.y,d.y, fmaf(d.z,d.z, fmaf(d.w,d.w, k2))));
    }
    #pragma unroll
    for (int off = 1; off < 64; off <<= 1) {
        q2 = fmaxf(q2, __shfl_xor(q2, off));
        k2 = fmaxf(k2, __shfl_xor(k2, off));
    }
    if ((threadIdx.x & 63) == 0) {
        atomicMax(ST + b,     __float_as_int(q2));
        atomicMax(ST + 2 + b, __float_as_int(k2));
    }
}

__device__ __forceinline__ float get_mhat(const int* ST, int b) {
    float q2 = __int_as_float(ST[b]);
    float k2 = __int_as_float(ST[2 + b]);
    return 0.125f * sqrtf(q2) * sqrtf(k2) + 1.0f;
}

// ---------------- K2: denominator partial sums L (no max tracking) ----------------
// grid 512 = 2b x 64 row-tiles(64) x 4 col-splits(1024). micro 4x4.
__global__ __launch_bounds__(256) void k_stats(
    const float* __restrict__ Q, const float* __restrict__ Kb,
    const int* __restrict__ ST, float* __restrict__ Lp)
{
    __shared__ float Qs[64][65];
    __shared__ float Ks[64][65];
    int gid = blockIdx.x;
    int cs  = gid & 3;
    int r   = gid >> 2;
    int b   = r >> 6;
    int n0  = (r & 63) * 64;
    int cb  = cs * 1024;
    float Mh = get_mhat(ST, b);

    int t  = threadIdx.x;
    int tx = t & 15, ty = t >> 4;       // col0 = 4tx, row0 = 4ty

    for (int idx = t; idx < 64 * 64; idx += 256) {
        int rr = idx >> 6, c = idx & 63;
        Qs[rr][c] = Q[((size_t)((b << 12) + n0 + rr)) * CCH + c];
    }

    float l0 = 0.f, l1 = 0.f, l2 = 0.f, l3 = 0.f;

    for (int ct = 0; ct < 1024; ct += 64) {
        __syncthreads();
        for (int idx = t; idx < 64 * 64; idx += 256) {
            int rr = idx >> 6, c = idx & 63;
            Ks[rr][c] = Kb[((size_t)((b << 12) + cb + ct + rr)) * CCH + c];
        }
        __syncthreads();
        float f[4][4] = {{0,0,0,0},{0,0,0,0},{0,0,0,0},{0,0,0,0}};
        #pragma unroll 4
        for (int k = 0; k < 64; ++k) {
            float q0 = Qs[4*ty+0][k], q1 = Qs[4*ty+1][k];
            float q2 = Qs[4*ty+2][k], q3 = Qs[4*ty+3][k];
            float c0 = Ks[4*tx+0][k], c1 = Ks[4*tx+1][k];
            float c2 = Ks[4*tx+2][k], c3 = Ks[4*tx+3][k];
            f[0][0]=fmaf(q0,c0,f[0][0]); f[0][1]=fmaf(q0,c1,f[0][1]);
            f[0][2]=fmaf(q0,c2,f[0][2]); f[0][3]=fmaf(q0,c3,f[0][3]);
            f[1][0]=fmaf(q1,c0,f[1][0]); f[1][1]=fmaf(q1,c1,f[1][1]);
            f[1][2]=fmaf(q1,c2,f[1][2]); f[1][3]=fmaf(q1,c3,f[1][3]);
            f[2][0]=fmaf(q2,c0,f[2][0]); f[2][1]=fmaf(q2,c1,f[2][1]);
            f[2][2]=fmaf(q2,c2,f[2][2]); f[2][3]=fmaf(q2,c3,f[2][3]);
            f[3][0]=fmaf(q3,c0,f[3][0]); f[3][1]=fmaf(q3,c1,f[3][1]);
            f[3][2]=fmaf(q3,c2,f[3][2]); f[3][3]=fmaf(q3,c3,f[3][3]);
        }
        l0 += __expf(f[0][0]*0.125f - Mh) + __expf(f[0][1]*0.125f - Mh)
            + __expf(f[0][2]*0.125f - Mh) + __expf(f[0][3]*0.125f - Mh);
        l1 += __expf(f[1][0]*0.125f - Mh) + __expf(f[1][1]*0.125f - Mh)
            + __expf(f[1][2]*0.125f - Mh) + __expf(f[1][3]*0.125f - Mh);
        l2 += __expf(f[2][0]*0.125f - Mh) + __expf(f[2][1]*0.125f - Mh)
            + __expf(f[2][2]*0.125f - Mh) + __expf(f[2][3]*0.125f - Mh);
        l3 += __expf(f[3][0]*0.125f - Mh) + __expf(f[3][1]*0.125f - Mh)
            + __expf(f[3][2]*0.125f - Mh) + __expf(f[3][3]*0.125f - Mh);
    }

    #pragma unroll
    for (int off = 1; off < 16; off <<= 1) {
        l0 += __shfl_xor(l0, off);
        l1 += __shfl_xor(l1, off);
        l2 += __shfl_xor(l2, off);
        l3 += __shfl_xor(l3, off);
    }
    if (tx == 0) {
        float* dst = Lp + ((size_t)(cs * 2 + b) << 12) + n0 + 4 * ty;
        dst[0] = l0; dst[1] = l1; dst[2] = l2; dst[3] = l3;
    }
}

// ---------------- K2.5: final local attention weights ----------------
// 256 thr = 4 pixels x 64 lanes (49 taps active).
__global__ __launch_bounds__(256) void k_attn(
    const float* __restrict__ Q, const float* __restrict__ Kb,
    const float* __restrict__ Lp, const int* __restrict__ ST,
    float* __restrict__ A)
{
    int t    = threadIdx.x;
    int lane = t & 63;
    int gp   = blockIdx.x * 4 + (t >> 6);   // b*4096+n
    int b = gp >> 12, n = gp & 4095;
    float Mh = get_mhat(ST, b);
    float L = Lp[((size_t)(0 * 2 + b) << 12) + n] + Lp[((size_t)(1 * 2 + b) << 12) + n]
            + Lp[((size_t)(2 * 2 + b) << 12) + n] + Lp[((size_t)(3 * 2 + b) << 12) + n];

    int tap = (lane < NTAP) ? lane : 48;
    int i = n >> 6, j = n & 63;
    int kk = tap / 7, ll = tap - kk * 7;
    int hi = min(max(i + kk - RAD, 0), 63);
    int wi = min(max(j + ll - RAD, 0), 63);
    int src = (hi << 6) + wi;

    const float4* q4 = (const float4*)(Q  + ((size_t)(b << 12) + n)   * CCH);
    const float4* k4 = (const float4*)(Kb + ((size_t)(b << 12) + src) * CCH);
    float d = 0.f;
    #pragma unroll
    for (int c = 0; c < 16; ++c) {
        float4 a = q4[c], e = k4[c];
        d = fmaf(a.x,e.x, fmaf(a.y,e.y, fmaf(a.z,e.z, fmaf(a.w,e.w, d))));
    }
    float dnn = __shfl(d, 24);              // center tap: src == n always
    float Lc  = L - __expf(dnn * 0.125f - Mh) + __expf(-Mh);
    float val = (src == n) ? 0.f : d * 0.125f;
    if (lane < NTAP)
        A[(size_t)gp * NTAP + tap] = __expf(val - Mh) / Lc;
}

// ---------------- K3: output conv-GEMM, in-block tap split ----------------
// grid 256 = 2b x 128 pixel-tiles(32). 512 thr: half h does taps h*25..,
// micro 2pix x 4och; LDS reduce + transposed coalesced store.
__global__ __launch_bounds__(512) void k_out(
    const float* __restrict__ A, const float* __restrict__ V,
    const float* __restrict__ Wt, const float* __restrict__ bout,
    float* __restrict__ out)
{
    __shared__ float Wsh[2][64][65];
    __shared__ float Rs[2][32][65];
    __shared__ float Al[32][NTAP];
    __shared__ float Racc[32][65];
    int gid = blockIdx.x;
    int b   = gid >> 7;
    int n0  = (gid & 127) * 32;
    int t    = threadIdx.x;
    int half = t >> 8;
    int tt   = t & 255;
    int tx = tt & 15, ty = tt >> 4;     // och0 = 4tx, pix0 = 2ty

    for (int idx = t; idx < 32 * NTAP; idx += 512) {
        int q = idx / NTAP, kl = idx - q * NTAP;
        Al[q][kl] = A[((size_t)((b << 12) + n0 + q)) * NTAP + kl];
    }

    float f00=0,f01=0,f02=0,f03=0,f10=0,f11=0,f12=0,f13=0;

    for (int tp = 0; tp < 25; ++tp) {
        int tap = half * 25 + tp;
        bool valid = tap < NTAP;
        __syncthreads();
        if (valid) {
            int kk = tap / 7, ll = tap - kk * 7;
            for (int idx = tt; idx < 64 * 64; idx += 256) {
                int o = idx >> 6, c = idx & 63;
                Wsh[half][o][c] = Wt[o * 3136 + tap * 64 + c];
            }
            for (int idx = tt; idx < 32 * 64; idx += 256) {
                int q = idx >> 6, c = idx & 63;
                int n = n0 + q;
                int i = n >> 6, j = n & 63;
                int hi = min(max(i + kk - RAD, 0), 63);
                int wi = min(max(j + ll - RAD, 0), 63);
                int src = (hi << 6) + wi;
                Rs[half][q][c] = Al[q][tap] * V[((size_t)((b << 12) + src)) * CCH + c];
            }
        }
        __syncthreads();
        if (valid) {
            #pragma unroll 4
            for (int k = 0; k < 64; ++k) {
                float r0 = Rs[half][2 * ty][k];
                float r1 = Rs[half][2 * ty + 1][k];
                float w0 = Wsh[half][4 * tx + 0][k];
                float w1 = Wsh[half][4 * tx + 1][k];
                float w2 = Wsh[half][4 * tx + 2][k];
                float w3 = Wsh[half][4 * tx + 3][k];
                f00 = fmaf(r0, w0, f00); f01 = fmaf(r0, w1, f01);
                f02 = fmaf(r0, w2, f02); f03 = fmaf(r0, w3, f03);
                f10 = fmaf(r1, w0, f10); f11 = fmaf(r1, w1, f11);
                f12 = fmaf(r1, w2, f12); f13 = fmaf(r1, w3, f13);
            }
        }
    }

    __syncthreads();
    if (half == 1) {
        Racc[2*ty  ][4*tx+0] = f00; Racc[2*ty  ][4*tx+1] = f01;
        Racc[2*ty  ][4*tx+2] = f02; Racc[2*ty  ][4*tx+3] = f03;
        Racc[2*ty+1][4*tx+0] = f10; Racc[2*ty+1][4*tx+1] = f11;
        Racc[2*ty+1][4*tx+2] = f12; Racc[2*ty+1][4*tx+3] = f13;
    }
    __syncthreads();
    if (half == 0) {
        float b0 = bout[4*tx+0], b1 = bout[4*tx+1], b2 = bout[4*tx+2], b3 = bout[4*tx+3];
        Racc[2*ty  ][4*tx+0] = fmaxf(f00 + Racc[2*ty  ][4*tx+0] + b0, 0.f);
        Racc[2*ty  ][4*tx+1] = fmaxf(f01 + Racc[2*ty  ][4*tx+1] + b1, 0.f);
        Racc[2*ty  ][4*tx+2] = fmaxf(f02 + Racc[2*ty  ][4*tx+2] + b2, 0.f);
        Racc[2*ty  ][4*tx+3] = fmaxf(f03 + Racc[2*ty  ][4*tx+3] + b3, 0.f);
        Racc[2*ty+1][4*tx+0] = fmaxf(f10 + Racc[2*ty+1][4*tx+0] + b0, 0.f);
        Racc[2*ty+1][4*tx+1] = fmaxf(f11 + Racc[2*ty+1][4*tx+1] + b1, 0.f);
        Racc[2*ty+1][4*tx+2] = fmaxf(f12 + Racc[2*ty+1][4*tx+2] + b2, 0.f);
        Racc[2*ty+1][4*tx+3] = fmaxf(f13 + Racc[2*ty+1][4*tx+3] + b3, 0.f);
    }
    __syncthreads();
    #pragma unroll
    for (int it = 0; it < 4; ++it) {
        int idx = t + it * 512;             // 2048 outputs
        int o = idx >> 5, nl = idx & 31;
        out[((size_t)((b << 6) + o) << 12) + n0 + nl] = Racc[nl][o];
    }
}

// ---------------- launch ----------------
extern "C" void kernel_launch(void* const* d_in, const int* in_sizes, int n_in,
                              void* d_out, int out_size, void* d_ws, size_t ws_size,
                              hipStream_t stream) {
    const float* x    = (const float*)d_in[0];
    const float* Wq   = (const float*)d_in[1];
    const float* bq   = (const float*)d_in[2];
    const float* Wk   = (const float*)d_in[3];
    const float* bk   = (const float*)d_in[4];
    const float* Wv   = (const float*)d_in[5];
    const float* bv   = (const float*)d_in[6];
    const float* Wp   = (const float*)d_in[7];
    const float* bp   = (const float*)d_in[8];
    const float* Wout = (const float*)d_in[9];
    const float* bout = (const float*)d_in[10];
    float* out = (float*)d_out;

    float* ws = (float*)d_ws;
    float* Wt = ws + WT0;
    float* Qb = ws + QB0;
    float* Kb = ws + KB0;
    float* Vb = ws + VB0;
    float* Lp = ws + LP0;
    float* A  = ws + A0;
    int*   ST = (int*)(ws + ST0);

    hipMemsetAsync(ST, 0, 16, stream);
    hipLaunchKernelGGL(k_twout, dim3(784),  dim3(256), 0, stream, Wout, Wt);
    hipLaunchKernelGGL(k_pos,   dim3(32),   dim3(256), 0, stream, Wp, bp, Qb, Kb, Vb);
    hipLaunchKernelGGL(k_qkv,   dim3(768),  dim3(256), 0, stream,
                       x, Wq, bq, Wk, bk, Wv, bv, Qb, Kb, Vb);
    hipLaunchKernelGGL(k_norm,  dim3(32),   dim3(256), 0, stream, Qb, Kb, ST);
    hipLaunchKernelGGL(k_stats, dim3(512),  dim3(256), 0, stream, Qb, Kb, ST, Lp);
    hipLaunchKernelGGL(k_attn,  dim3(2048), dim3(256), 0, stream, Qb, Kb, Lp, ST, A);
    hipLaunchKernelGGL(k_out,   dim3(256),  dim3(512), 0, stream, A, Vb, Wt, bout, out);
}

// Round 4
// 148.484 us; speedup vs baseline: 3.9868x; 2.1524x over previous
//
#include <hip/hip_runtime.h>
#include <math.h>

// Problem constants (b=2, cin=256, h=w=64, C=64, qc=60, pd=4, OUT_K=7)
#define HWN 4096
#define CIN 256
#define CCH 64
#define QC  60
#define NTAP 49

typedef short bf16x8 __attribute__((ext_vector_type(8)));
typedef float f32x4  __attribute__((ext_vector_type(4)));

__device__ __forceinline__ float b2f(ushort u) {
    return __uint_as_float(((unsigned)u) << 16);
}
__device__ __forceinline__ ushort f2b(float f) {
    unsigned u = __float_as_uint(f);
    return (ushort)((u + 0x7FFFu + ((u >> 16) & 1u)) >> 16);
}
__device__ __forceinline__ unsigned pk2(float a, float b) {
    return (unsigned)f2b(a) | ((unsigned)f2b(b) << 16);
}
__device__ __forceinline__ int iclamp(int x) { return min(max(x, 0), 63); }

// ws layout (byte offsets), total ~5.2 MB
#define WTB_OFF 0u           // bf16 [kl*64+o][64c]   401408 B
#define QH_OFF  401408u      // bf16 [b*4096+n][64]  1048576 B
#define KH_OFF  1449984u
#define VH_OFF  2498560u
#define LP_OFF  3547136u     // f32 [cs*2+b][4096]     65536 B
#define AB_OFF  3612672u     // f32 [b*4096+n][49]   1605632 B
#define ST_OFF  5218304u     // 4 ints

// ---------------- K0: Wout (o,c,kl) -> Wtb bf16 [(kl*64+o)][c] ----------------
__global__ __launch_bounds__(256) void k_twout(const float* __restrict__ Wout,
                                               ushort* __restrict__ Wtb) {
    int idx = blockIdx.x * 256 + threadIdx.x;
    if (idx >= 64 * 64 * NTAP) return;
    int o   = idx / (64 * NTAP);
    int rem = idx - o * (64 * NTAP);
    int c   = rem / NTAP;
    int kl  = rem - c * NTAP;
    Wtb[(kl * 64 + o) * 64 + c] = f2b(Wout[idx]);
}

// ---------------- K0b: positional channels 60..63 (bf16) ----------------
__global__ __launch_bounds__(256) void k_pos(
    const float* __restrict__ Wp, const float* __restrict__ bp,
    ushort* __restrict__ QH, ushort* __restrict__ KH, ushort* __restrict__ VH)
{
    int idx = blockIdx.x * 256 + threadIdx.x;   // 8192 = b*4096+n
    int n = idx & 4095;
    float fi = (float)(n >> 6), fj = (float)(n & 63);
    float p0 = fmaf(Wp[0], fi, fmaf(Wp[1], fj, bp[0]));
    float p1 = fmaf(Wp[2], fi, fmaf(Wp[3], fj, bp[1]));
    float p2 = fmaf(Wp[4], fi, fmaf(Wp[5], fj, bp[2]));
    float p3 = fmaf(Wp[6], fi, fmaf(Wp[7], fj, bp[3]));
    uint2 pv = make_uint2(pk2(p0, p1), pk2(p2, p3));
    size_t off = (size_t)idx * CCH + QC;
    *(uint2*)(QH + off) = pv;
    *(uint2*)(KH + off) = pv;
    *(uint2*)(VH + off) = pv;
}

// ---------------- K1: QKV projection (ch 0..59), fp32 compute, bf16 out ----------------
// grid 384 = 3 mats x 2b x 64 pixel-tiles(64). 256 thr, micro 4pix x 4ch.
__global__ __launch_bounds__(256) void k_qkv(
    const float* __restrict__ x,
    const float* __restrict__ Wq, const float* __restrict__ bq,
    const float* __restrict__ Wk, const float* __restrict__ bk,
    const float* __restrict__ Wv, const float* __restrict__ bv,
    ushort* __restrict__ QH, ushort* __restrict__ KH, ushort* __restrict__ VH)
{
    __shared__ float Xs[64][68];   // [k][pix]
    __shared__ float Ws[64][68];   // [k][och]
    int bid  = blockIdx.x;
    int mat  = bid % 3;
    int rest = bid / 3;
    int b    = rest >> 6;
    int n0   = (rest & 63) * 64;
    const float* Wm = (mat == 0) ? Wq : (mat == 1) ? Wk : Wv;
    const float* bm = (mat == 0) ? bq : (mat == 1) ? bk : bv;
    ushort*      Ob = (mat == 0) ? QH : (mat == 1) ? KH : VH;

    int t  = threadIdx.x;
    int tx = t & 15, ty = t >> 4;       // och0 = 4tx, pix0 = 4ty
    float f[4][4] = {{0,0,0,0},{0,0,0,0},{0,0,0,0},{0,0,0,0}};

    for (int c0 = 0; c0 < CIN; c0 += 64) {
        __syncthreads();
        for (int idx = t; idx < 64 * 64; idx += 256) {
            int k = idx >> 6, p = idx & 63;
            Xs[k][p] = x[((size_t)(b * CIN + c0 + k) << 12) + n0 + p];
        }
        for (int idx = t; idx < 64 * 64; idx += 256) {
            int o = idx & 63, k = idx >> 6;
            Ws[k][o] = (o < QC) ? Wm[o * CIN + c0 + k] : 0.f;
        }
        __syncthreads();
        #pragma unroll 4
        for (int k = 0; k < 64; ++k) {
            const float4 xv = *(const float4*)(&Xs[k][4 * ty]);
            const float4 wv = *(const float4*)(&Ws[k][4 * tx]);
            f[0][0]=fmaf(xv.x,wv.x,f[0][0]); f[0][1]=fmaf(xv.x,wv.y,f[0][1]);
            f[0][2]=fmaf(xv.x,wv.z,f[0][2]); f[0][3]=fmaf(xv.x,wv.w,f[0][3]);
            f[1][0]=fmaf(xv.y,wv.x,f[1][0]); f[1][1]=fmaf(xv.y,wv.y,f[1][1]);
            f[1][2]=fmaf(xv.y,wv.z,f[1][2]); f[1][3]=fmaf(xv.y,wv.w,f[1][3]);
            f[2][0]=fmaf(xv.z,wv.x,f[2][0]); f[2][1]=fmaf(xv.z,wv.y,f[2][1]);
            f[2][2]=fmaf(xv.z,wv.z,f[2][2]); f[2][3]=fmaf(xv.z,wv.w,f[2][3]);
            f[3][0]=fmaf(xv.w,wv.x,f[3][0]); f[3][1]=fmaf(xv.w,wv.y,f[3][1]);
            f[3][2]=fmaf(xv.w,wv.z,f[3][2]); f[3][3]=fmaf(xv.w,wv.w,f[3][3]);
        }
    }
    if (tx < 15) {                       // och 60..63 are pos channels
        float4 bb = *(const float4*)(bm + 4 * tx);
        #pragma unroll
        for (int p = 0; p < 4; ++p) {
            int n = n0 + 4 * ty + p;
            uint2 v = make_uint2(pk2(f[p][0] + bb.x, f[p][1] + bb.y),
                                 pk2(f[p][2] + bb.z, f[p][3] + bb.w));
            *(uint2*)(Ob + ((size_t)((b << 12) + n)) * CCH + 4 * tx) = v;
        }
    }
}

// ---------------- K1b: per-batch max |q|^2, |k|^2 ----------------
__global__ __launch_bounds__(256) void k_norm(
    const ushort* __restrict__ QH, const ushort* __restrict__ KH,
    int* __restrict__ ST)
{
    int idx = blockIdx.x * 256 + threadIdx.x;   // 8192
    int b = idx >> 12;
    float q2 = 0.f, k2 = 0.f;
    #pragma unroll
    for (int c8 = 0; c8 < 8; ++c8) {
        bf16x8 qv = *(const bf16x8*)(QH + (size_t)idx * CCH + c8 * 8);
        bf16x8 kv = *(const bf16x8*)(KH + (size_t)idx * CCH + c8 * 8);
        #pragma unroll
        for (int e = 0; e < 8; ++e) {
            float qf = b2f((ushort)qv[e]), kf = b2f((ushort)kv[e]);
            q2 = fmaf(qf, qf, q2);
            k2 = fmaf(kf, kf, k2);
        }
    }
    #pragma unroll
    for (int off = 1; off < 64; off <<= 1) {
        q2 = fmaxf(q2, __shfl_xor(q2, off, 64));
        k2 = fmaxf(k2, __shfl_xor(k2, off, 64));
    }
    if ((threadIdx.x & 63) == 0) {
        atomicMax(ST + b,     __float_as_int(q2));
        atomicMax(ST + 2 + b, __float_as_int(k2));
    }
}

__device__ __forceinline__ float get_mhat(const int* ST, int b) {
    float q2 = __int_as_float(ST[b]);
    float k2 = __int_as_float(ST[2 + b]);
    return 0.125f * sqrtf(q2) * sqrtf(k2) + 1.0f;
}

// ---------------- K2: softmax denominator partials via MFMA ----------------
// grid 256 = 2 keysplit x 2b x 64 rowtiles(64). 256 thr = 4 waves,
// wave strip = 16 rows x 64 keys per chunk, frags straight from global (L2).
__global__ __launch_bounds__(256) void k_stats(
    const ushort* __restrict__ QH, const ushort* __restrict__ KH,
    const int* __restrict__ ST, float* __restrict__ Lp)
{
    int bid = blockIdx.x;
    int cs  = bid & 1;
    int r   = bid >> 1;
    int b   = r >> 6;
    int n0  = (r & 63) * 64;
    float Mh = get_mhat(ST, b);

    int t = threadIdx.x;
    int w = t >> 6, L = t & 63;
    int lrow = L & 15, lk = L >> 4;

    // A-frags: Q rows n0 + w*16 + lrow, k-chunks 0/1
    size_t qbase = ((size_t)((b << 12) + n0 + w * 16 + lrow)) * CCH + lk * 8;
    bf16x8 a0 = *(const bf16x8*)(QH + qbase);
    bf16x8 a1 = *(const bf16x8*)(QH + qbase + 32);

    float rs0 = 0.f, rs1 = 0.f, rs2 = 0.f, rs3 = 0.f;

    for (int m0 = cs * 2048; m0 < cs * 2048 + 2048; m0 += 64) {
        f32x4 acc[4];
        #pragma unroll
        for (int cf = 0; cf < 4; ++cf) {
            size_t kb = ((size_t)((b << 12) + m0 + cf * 16 + lrow)) * CCH + lk * 8;
            bf16x8 b0 = *(const bf16x8*)(KH + kb);
            bf16x8 b1 = *(const bf16x8*)(KH + kb + 32);
            f32x4 z = {0.f, 0.f, 0.f, 0.f};
            z = __builtin_amdgcn_mfma_f32_16x16x32_bf16(a0, b0, z, 0, 0, 0);
            z = __builtin_amdgcn_mfma_f32_16x16x32_bf16(a1, b1, z, 0, 0, 0);
            acc[cf] = z;
        }
        #pragma unroll
        for (int cf = 0; cf < 4; ++cf) {
            rs0 += __expf(acc[cf][0] * 0.125f - Mh);
            rs1 += __expf(acc[cf][1] * 0.125f - Mh);
            rs2 += __expf(acc[cf][2] * 0.125f - Mh);
            rs3 += __expf(acc[cf][3] * 0.125f - Mh);
        }
    }
    // reduce over the 16 column-lanes
    #pragma unroll
    for (int off = 1; off < 16; off <<= 1) {
        rs0 += __shfl_xor(rs0, off, 64);
        rs1 += __shfl_xor(rs1, off, 64);
        rs2 += __shfl_xor(rs2, off, 64);
        rs3 += __shfl_xor(rs3, off, 64);
    }
    if (lrow == 0) {
        int n = n0 + w * 16 + lk * 4;   // D rows: (L>>4)*4 + reg
        float* dst = Lp + ((size_t)(cs * 2 + b) << 12) + n;
        dst[0] = rs0; dst[1] = rs1; dst[2] = rs2; dst[3] = rs3;
    }
}

// ---------------- K2.5: final local attention weights ----------------
__global__ __launch_bounds__(256) void k_attn(
    const ushort* __restrict__ QH, const ushort* __restrict__ KH,
    const float* __restrict__ Lp, const int* __restrict__ ST,
    float* __restrict__ A)
{
    int t    = threadIdx.x;
    int lane = t & 63;
    int gp   = blockIdx.x * 4 + (t >> 6);   // b*4096+n
    int b = gp >> 12, n = gp & 4095;
    float Mh = get_mhat(ST, b);
    float L = Lp[((size_t)b << 12) + n] + Lp[((size_t)(2 + b) << 12) + n];

    int tap = (lane < NTAP) ? lane : 48;
    int i = n >> 6, j = n & 63;
    int kk = tap / 7, ll = tap - kk * 7;
    int src = (iclamp(i + kk - 3) << 6) + iclamp(j + ll - 3);

    const ushort* qr = QH + ((size_t)(b << 12) + n)   * CCH;
    const ushort* kr = KH + ((size_t)(b << 12) + src) * CCH;
    float d = 0.f;
    #pragma unroll
    for (int c8 = 0; c8 < 8; ++c8) {
        bf16x8 qv = *(const bf16x8*)(qr + c8 * 8);
        bf16x8 kv = *(const bf16x8*)(kr + c8 * 8);
        #pragma unroll
        for (int e = 0; e < 8; ++e)
            d = fmaf(b2f((ushort)qv[e]), b2f((ushort)kv[e]), d);
    }
    float dnn = __shfl(d, 24, 64);          // center tap (3,3): src == n
    float Lc  = L - __expf(dnn * 0.125f - Mh) + __expf(-Mh);
    float val = (src == n) ? 0.f : d * 0.125f;
    if (lane < NTAP)
        A[(size_t)gp * NTAP + tap] = __expf(val - Mh) / Lc;
}

// ---------------- K3: output conv via per-tap MFMA ----------------
// grid 256 = 2b x 64 rows x 2 col-halves. 256 thr = 4 waves.
// Wave tile 16q x 32o; V halo (7 rows x 38 cols) in swizzled LDS.
__global__ __launch_bounds__(256) void k_out(
    const float* __restrict__ A, const ushort* __restrict__ VH,
    const ushort* __restrict__ Wtb, const float* __restrict__ bout,
    float* __restrict__ out)
{
    __shared__ ushort Vs[7 * 40 * 64];    // byte: kk*5120 + u*128 + swz(16B granule)
    __shared__ float  Al[32][51];
    int bid = blockIdx.x;
    int b   = bid >> 7;
    int rem = bid & 127;
    int i   = rem >> 1;
    int j0  = (rem & 1) * 32;

    int t = threadIdx.x;
    // stage V halo: granules (kk, u<38, c8<8), each 8 bf16 = 16B
    for (int g = t; g < 7 * 38 * 8; g += 256) {
        int kk = g / 304;
        int r2 = g - kk * 304;
        int u  = r2 >> 3, c8 = r2 & 7;
        int vr = iclamp(i + kk - 3);
        int vc = iclamp(j0 - 3 + u);
        bf16x8 val = *(const bf16x8*)(VH + ((size_t)((b << 12) + (vr << 6) + vc)) * CCH + c8 * 8);
        *(bf16x8*)((char*)Vs + kk * 5120 + u * 128 + ((c8 * 16) ^ ((u & 7) << 4))) = val;
    }
    for (int g = t; g < 32 * NTAP; g += 256) {
        int q = g / NTAP, kl = g - q * NTAP;
        Al[q][kl] = A[((size_t)((b << 12) + (i << 6) + j0 + q)) * NTAP + kl];
    }
    __syncthreads();

    int w = t >> 6, L = t & 63;
    int q16 = (w >> 1) << 4;            // 0 or 16
    int o32 = (w & 1) << 5;             // 0 or 32
    int lrow = L & 15, lk = L >> 4;

    f32x4 acc0 = {0.f, 0.f, 0.f, 0.f};
    f32x4 acc1 = {0.f, 0.f, 0.f, 0.f};

    for (int kk = 0; kk < 7; ++kk) {
        for (int ll = 0; ll < 7; ++ll) {
            int kl = kk * 7 + ll;
            float a = Al[q16 + lrow][kl];
            int u = q16 + lrow + ll;
            const char* vb = (const char*)Vs + kk * 5120 + u * 128;
            int swz = (u & 7) << 4;
            bf16x8 v0 = *(const bf16x8*)(vb + ((lk * 16) ^ swz));
            bf16x8 v1 = *(const bf16x8*)(vb + ((64 + lk * 16) ^ swz));
            bf16x8 af0, af1;
            #pragma unroll
            for (int e = 0; e < 8; ++e) {
                af0[e] = (short)f2b(b2f((ushort)v0[e]) * a);
                af1[e] = (short)f2b(b2f((ushort)v1[e]) * a);
            }
            size_t wb0 = ((size_t)(kl * 64 + o32 + lrow)) * 64 + lk * 8;
            size_t wb1 = ((size_t)(kl * 64 + o32 + 16 + lrow)) * 64 + lk * 8;
            bf16x8 b00 = *(const bf16x8*)(Wtb + wb0);
            bf16x8 b01 = *(const bf16x8*)(Wtb + wb0 + 32);
            bf16x8 b10 = *(const bf16x8*)(Wtb + wb1);
            bf16x8 b11 = *(const bf16x8*)(Wtb + wb1 + 32);
            acc0 = __builtin_amdgcn_mfma_f32_16x16x32_bf16(af0, b00, acc0, 0, 0, 0);
            acc0 = __builtin_amdgcn_mfma_f32_16x16x32_bf16(af1, b01, acc0, 0, 0, 0);
            acc1 = __builtin_amdgcn_mfma_f32_16x16x32_bf16(af0, b10, acc1, 0, 0, 0);
            acc1 = __builtin_amdgcn_mfma_f32_16x16x32_bf16(af1, b11, acc1, 0, 0, 0);
        }
    }

    // epilogue: bias + relu; D frag: col o = lane&15, rows q = (lane>>4)*4 + reg
    int nbase = (i << 6) + j0 + q16 + lk * 4;
    {
        int o = o32 + lrow;
        float bb = bout[o];
        float4 v = make_float4(fmaxf(acc0[0] + bb, 0.f), fmaxf(acc0[1] + bb, 0.f),
                               fmaxf(acc0[2] + bb, 0.f), fmaxf(acc0[3] + bb, 0.f));
        *(float4*)(out + (((size_t)(b * 64 + o)) << 12) + nbase) = v;
    }
    {
        int o = o32 + 16 + lrow;
        float bb = bout[o];
        float4 v = make_float4(fmaxf(acc1[0] + bb, 0.f), fmaxf(acc1[1] + bb, 0.f),
                               fmaxf(acc1[2] + bb, 0.f), fmaxf(acc1[3] + bb, 0.f));
        *(float4*)(out + (((size_t)(b * 64 + o)) << 12) + nbase) = v;
    }
}

// ---------------- launch ----------------
extern "C" void kernel_launch(void* const* d_in, const int* in_sizes, int n_in,
                              void* d_out, int out_size, void* d_ws, size_t ws_size,
                              hipStream_t stream) {
    const float* x    = (const float*)d_in[0];
    const float* Wq   = (const float*)d_in[1];
    const float* bq   = (const float*)d_in[2];
    const float* Wk   = (const float*)d_in[3];
    const float* bk   = (const float*)d_in[4];
    const float* Wv   = (const float*)d_in[5];
    const float* bv   = (const float*)d_in[6];
    const float* Wp   = (const float*)d_in[7];
    const float* bp   = (const float*)d_in[8];
    const float* Wout = (const float*)d_in[9];
    const float* bout = (const float*)d_in[10];
    float* out = (float*)d_out;

    char* ws = (char*)d_ws;
    ushort* Wtb = (ushort*)(ws + WTB_OFF);
    ushort* QH  = (ushort*)(ws + QH_OFF);
    ushort* KH  = (ushort*)(ws + KH_OFF);
    ushort* VH  = (ushort*)(ws + VH_OFF);
    float*  Lp  = (float*)(ws + LP_OFF);
    float*  A   = (float*)(ws + AB_OFF);
    int*    ST  = (int*)(ws + ST_OFF);

    hipMemsetAsync(ST, 0, 16, stream);
    hipLaunchKernelGGL(k_twout, dim3(784),  dim3(256), 0, stream, Wout, Wtb);
    hipLaunchKernelGGL(k_pos,   dim3(32),   dim3(256), 0, stream, Wp, bp, QH, KH, VH);
    hipLaunchKernelGGL(k_qkv,   dim3(384),  dim3(256), 0, stream,
                       x, Wq, bq, Wk, bk, Wv, bv, QH, KH, VH);
    hipLaunchKernelGGL(k_norm,  dim3(32),   dim3(256), 0, stream, QH, KH, ST);
    hipLaunchKernelGGL(k_stats, dim3(256),  dim3(256), 0, stream, QH, KH, ST, Lp);
    hipLaunchKernelGGL(k_attn,  dim3(2048), dim3(256), 0, stream, QH, KH, Lp, ST, A);
    hipLaunchKernelGGL(k_out,   dim3(256),  dim3(256), 0, stream, A, VH, Wtb, bout, out);
}

// Round 5
// 102.273 us; speedup vs baseline: 5.7881x; 1.4518x over previous
//
#include <hip/hip_runtime.h>
#include <math.h>

// Problem constants (b=2, cin=256, h=w=64, C=64, qc=60, pd=4, OUT_K=7)
#define NTAP 49

typedef short bf16x8 __attribute__((ext_vector_type(8)));
typedef float f32x4  __attribute__((ext_vector_type(4)));

__device__ __forceinline__ float b2f(ushort u) {
    return __uint_as_float(((unsigned)u) << 16);
}
__device__ __forceinline__ ushort f2b(float f) {
    unsigned u = __float_as_uint(f);
    return (ushort)((u + 0x7FFFu + ((u >> 16) & 1u)) >> 16);
}
__device__ __forceinline__ int iclamp(int x) { return min(max(x, 0), 63); }

// ws byte offsets (total ~5.5 MB)
#define WTB_OFF 0u           // bf16 [(kl*64+o)][64c]           401408 B
#define WAH_OFF 401408u      // bf16 [192 och][256 c] hi         98304 B
#define WAL_OFF 499712u      // bf16 [192 och][256 c] lo         98304 B
#define QH_OFF  598016u      // bf16 [b*4096+n][64]            1048576 B
#define KH_OFF  1646592u
#define VH_OFF  2695168u
#define LP_OFF  3743744u     // f32 [cs*2+b][4096], cs<4        131072 B
#define AB_OFF  3874816u     // f32 [b*4096+n][49]             1605632 B
#define ST_OFF  5480448u     // 4 ints

// ---------------- K0: Wout (o,c,kl) -> Wtb bf16 [(kl*64+o)][c] ----------------
__global__ __launch_bounds__(256) void k_twout(const float* __restrict__ Wout,
                                               ushort* __restrict__ Wtb) {
    int idx = blockIdx.x * 256 + threadIdx.x;
    if (idx >= 64 * 64 * NTAP) return;
    int o   = idx / (64 * NTAP);
    int rem = idx - o * (64 * NTAP);
    int c   = rem / NTAP;
    int kl  = rem - c * NTAP;
    Wtb[(kl * 64 + o) * 64 + c] = f2b(Wout[idx]);
}

// ---------------- K0b: split projection weights -> WAh/WAl [192][256] ----------------
// och m = mat*64 + o; o>=60 rows are zero (pos channels bypass the GEMM).
__global__ __launch_bounds__(256) void k_wsplit(
    const float* __restrict__ Wq, const float* __restrict__ Wk, const float* __restrict__ Wv,
    ushort* __restrict__ WAh, ushort* __restrict__ WAl)
{
    int idx = blockIdx.x * 256 + threadIdx.x;   // 192*256
    int m = idx >> 8, c = idx & 255;
    int mat = m >> 6, o = m & 63;
    float v = 0.f;
    if (o < 60) {
        const float* Wm = (mat == 0) ? Wq : (mat == 1) ? Wk : Wv;
        v = Wm[o * 256 + c];
    }
    ushort h = f2b(v);
    WAh[idx] = h;
    WAl[idx] = f2b(v - b2f(h));
}

// ---------------- K1: QKV projection via split-bf16 MFMA ----------------
// grid 256 = 2b x 128 pixel-tiles(32). 256 thr = 4 waves, wave = 32px x 48och.
// D = X*W^T: A-frags from swizzled LDS (x hi/lo), B-frags from L2 (WAh/WAl).
__global__ __launch_bounds__(256) void k_qkv(
    const float* __restrict__ x,
    const ushort* __restrict__ WAh, const ushort* __restrict__ WAl,
    const float* __restrict__ bq, const float* __restrict__ bk, const float* __restrict__ bv,
    const float* __restrict__ Wp, const float* __restrict__ bp,
    ushort* __restrict__ QKV)    // Q base; K=+524288, V=+1048576 (ushort elems)
{
    __shared__ ushort Xh[32 * 256];
    __shared__ ushort Xl[32 * 256];
    int bid = blockIdx.x;
    int b   = bid >> 7;
    int n0  = (bid & 127) * 32;
    int t   = threadIdx.x;

    // ---- stage x tile (32 px x 256 c) as hi/lo bf16, XOR-swizzled 16B granules ----
    {
        int p   = t & 31;
        int cg0 = t >> 5;
        #pragma unroll
        for (int it = 0; it < 4; ++it) {
            int cg = cg0 + it * 8;          // granule: c = cg*8 .. cg*8+7
            float v[8];
            #pragma unroll
            for (int e = 0; e < 8; ++e)
                v[e] = x[((size_t)(b * 256 + cg * 8 + e) << 12) + n0 + p];
            bf16x8 hi, lo;
            #pragma unroll
            for (int e = 0; e < 8; ++e) {
                ushort h = f2b(v[e]);
                hi[e] = (short)h;
                lo[e] = (short)f2b(v[e] - b2f(h));
            }
            int off = p * 256 + ((cg * 8) ^ ((p & 7) * 8));
            *(bf16x8*)(Xh + off) = hi;
            *(bf16x8*)(Xl + off) = lo;
        }
    }
    __syncthreads();

    int w = t >> 6, L = t & 63;
    int lrow = L & 15, lk = L >> 4;
    int ob = w * 48;                        // och quarter base (0,48,96,144)
    int px0 = lrow, px1 = 16 + lrow;

    f32x4 acc[2][3] = {{{0,0,0,0},{0,0,0,0},{0,0,0,0}},
                       {{0,0,0,0},{0,0,0,0},{0,0,0,0}}};

    #pragma unroll 2
    for (int c8 = 0; c8 < 8; ++c8) {
        int cidx = (c8 * 4 + lk) * 8;       // ushort offset of the 8-elem granule
        int o0 = px0 * 256 + (cidx ^ ((px0 & 7) * 8));
        int o1 = px1 * 256 + (cidx ^ ((px1 & 7) * 8));
        bf16x8 ah0 = *(const bf16x8*)(Xh + o0);
        bf16x8 al0 = *(const bf16x8*)(Xl + o0);
        bf16x8 ah1 = *(const bf16x8*)(Xh + o1);
        bf16x8 al1 = *(const bf16x8*)(Xl + o1);
        #pragma unroll
        for (int c = 0; c < 3; ++c) {
            int woff = (ob + c * 16 + lrow) * 256 + c8 * 32 + lk * 8;
            bf16x8 bh = *(const bf16x8*)(WAh + woff);
            bf16x8 bl = *(const bf16x8*)(WAl + woff);
            acc[0][c] = __builtin_amdgcn_mfma_f32_16x16x32_bf16(al0, bh, acc[0][c], 0, 0, 0);
            acc[0][c] = __builtin_amdgcn_mfma_f32_16x16x32_bf16(ah0, bl, acc[0][c], 0, 0, 0);
            acc[0][c] = __builtin_amdgcn_mfma_f32_16x16x32_bf16(ah0, bh, acc[0][c], 0, 0, 0);
            acc[1][c] = __builtin_amdgcn_mfma_f32_16x16x32_bf16(al1, bh, acc[1][c], 0, 0, 0);
            acc[1][c] = __builtin_amdgcn_mfma_f32_16x16x32_bf16(ah1, bl, acc[1][c], 0, 0, 0);
            acc[1][c] = __builtin_amdgcn_mfma_f32_16x16x32_bf16(ah1, bh, acc[1][c], 0, 0, 0);
        }
    }

    // ---- epilogue: bias or positional channel, store bf16 ----
    #pragma unroll
    for (int g = 0; g < 2; ++g) {
        #pragma unroll
        for (int c = 0; c < 3; ++c) {
            int och = ob + c * 16 + lrow;
            int mat = och >> 6;
            int o   = och & 63;
            const float* bm = (mat == 0) ? bq : (mat == 1) ? bk : bv;
            ushort* Ob = QKV + (size_t)mat * 524288;
            if (o < 60) {
                float bias = bm[o];
                #pragma unroll
                for (int e = 0; e < 4; ++e) {
                    int n = n0 + g * 16 + lk * 4 + e;
                    Ob[((size_t)((b << 12) + n)) * 64 + o] = f2b(acc[g][c][e] + bias);
                }
            } else {
                int po = o - 60;
                float w0 = Wp[2 * po], w1 = Wp[2 * po + 1], b0 = bp[po];
                #pragma unroll
                for (int e = 0; e < 4; ++e) {
                    int n = n0 + g * 16 + lk * 4 + e;
                    float fi = (float)(n >> 6), fj = (float)(n & 63);
                    Ob[((size_t)((b << 12) + n)) * 64 + o] = f2b(fmaf(w0, fi, fmaf(w1, fj, b0)));
                }
            }
        }
    }
}

// ---------------- K1b: per-batch max |q|^2, |k|^2 ----------------
__global__ __launch_bounds__(128) void k_norm(
    const ushort* __restrict__ QH, const ushort* __restrict__ KH,
    int* __restrict__ ST)
{
    int idx = blockIdx.x * 128 + threadIdx.x;   // 8192 rows
    int b = idx >> 12;
    float q2 = 0.f, k2 = 0.f;
    #pragma unroll
    for (int c8 = 0; c8 < 8; ++c8) {
        bf16x8 qv = *(const bf16x8*)(QH + (size_t)idx * 64 + c8 * 8);
        bf16x8 kv = *(const bf16x8*)(KH + (size_t)idx * 64 + c8 * 8);
        #pragma unroll
        for (int e = 0; e < 8; ++e) {
            float qf = b2f((ushort)qv[e]), kf = b2f((ushort)kv[e]);
            q2 = fmaf(qf, qf, q2);
            k2 = fmaf(kf, kf, k2);
        }
    }
    #pragma unroll
    for (int off = 1; off < 64; off <<= 1) {
        q2 = fmaxf(q2, __shfl_xor(q2, off, 64));
        k2 = fmaxf(k2, __shfl_xor(k2, off, 64));
    }
    if ((threadIdx.x & 63) == 0) {
        atomicMax(ST + b,     __float_as_int(q2));
        atomicMax(ST + 2 + b, __float_as_int(k2));
    }
}

__device__ __forceinline__ float get_mhat(const int* ST, int b) {
    float q2 = __int_as_float(ST[b]);
    float k2 = __int_as_float(ST[2 + b]);
    return 0.125f * sqrtf(q2) * sqrtf(k2) + 1.0f;
}

// ---------------- K2: softmax denominator partials via MFMA ----------------
// grid 512 = 4 keysplit x 2b x 64 rowtiles(64). 256 thr = 4 waves.
__global__ __launch_bounds__(256) void k_stats(
    const ushort* __restrict__ QH, const ushort* __restrict__ KH,
    const int* __restrict__ ST, float* __restrict__ Lp)
{
    int bid = blockIdx.x;
    int cs  = bid & 3;
    int r   = bid >> 2;
    int b   = r >> 6;
    int n0  = (r & 63) * 64;
    float Mh = get_mhat(ST, b);

    int t = threadIdx.x;
    int w = t >> 6, L = t & 63;
    int lrow = L & 15, lk = L >> 4;

    size_t qbase = ((size_t)((b << 12) + n0 + w * 16 + lrow)) * 64 + lk * 8;
    bf16x8 a0 = *(const bf16x8*)(QH + qbase);
    bf16x8 a1 = *(const bf16x8*)(QH + qbase + 32);

    float rs0 = 0.f, rs1 = 0.f, rs2 = 0.f, rs3 = 0.f;

    #pragma unroll 2
    for (int m0 = cs * 1024; m0 < cs * 1024 + 1024; m0 += 64) {
        f32x4 acc[4];
        #pragma unroll
        for (int cf = 0; cf < 4; ++cf) {
            size_t kb = ((size_t)((b << 12) + m0 + cf * 16 + lrow)) * 64 + lk * 8;
            bf16x8 b0 = *(const bf16x8*)(KH + kb);
            bf16x8 b1 = *(const bf16x8*)(KH + kb + 32);
            f32x4 z = {0.f, 0.f, 0.f, 0.f};
            z = __builtin_amdgcn_mfma_f32_16x16x32_bf16(a0, b0, z, 0, 0, 0);
            z = __builtin_amdgcn_mfma_f32_16x16x32_bf16(a1, b1, z, 0, 0, 0);
            acc[cf] = z;
        }
        #pragma unroll
        for (int cf = 0; cf < 4; ++cf) {
            rs0 += __expf(acc[cf][0] * 0.125f - Mh);
            rs1 += __expf(acc[cf][1] * 0.125f - Mh);
            rs2 += __expf(acc[cf][2] * 0.125f - Mh);
            rs3 += __expf(acc[cf][3] * 0.125f - Mh);
        }
    }
    #pragma unroll
    for (int off = 1; off < 16; off <<= 1) {
        rs0 += __shfl_xor(rs0, off, 64);
        rs1 += __shfl_xor(rs1, off, 64);
        rs2 += __shfl_xor(rs2, off, 64);
        rs3 += __shfl_xor(rs3, off, 64);
    }
    if (lrow == 0) {
        int n = n0 + w * 16 + lk * 4;
        float* dst = Lp + ((size_t)(cs * 2 + b) << 12) + n;
        dst[0] = rs0; dst[1] = rs1; dst[2] = rs2; dst[3] = rs3;
    }
}

// ---------------- K2.5: final local attention weights ----------------
__global__ __launch_bounds__(256) void k_attn(
    const ushort* __restrict__ QH, const ushort* __restrict__ KH,
    const float* __restrict__ Lp, const int* __restrict__ ST,
    float* __restrict__ A)
{
    int t    = threadIdx.x;
    int lane = t & 63;
    int gp   = blockIdx.x * 4 + (t >> 6);   // b*4096+n
    int b = gp >> 12, n = gp & 4095;
    float Mh = get_mhat(ST, b);
    float L = Lp[((size_t)(0 + b) << 12) + n] + Lp[((size_t)(2 + b) << 12) + n]
            + Lp[((size_t)(4 + b) << 12) + n] + Lp[((size_t)(6 + b) << 12) + n];

    int tap = (lane < NTAP) ? lane : 48;
    int i = n >> 6, j = n & 63;
    int kk = tap / 7, ll = tap - kk * 7;
    int src = (iclamp(i + kk - 3) << 6) + iclamp(j + ll - 3);

    const ushort* qr = QH + ((size_t)(b << 12) + n)   * 64;
    const ushort* kr = KH + ((size_t)(b << 12) + src) * 64;
    float d = 0.f;
    #pragma unroll
    for (int c8 = 0; c8 < 8; ++c8) {
        bf16x8 qv = *(const bf16x8*)(qr + c8 * 8);
        bf16x8 kv = *(const bf16x8*)(kr + c8 * 8);
        #pragma unroll
        for (int e = 0; e < 8; ++e)
            d = fmaf(b2f((ushort)qv[e]), b2f((ushort)kv[e]), d);
    }
    float dnn = __shfl(d, 24, 64);          // center tap (3,3): src == n
    float Lc  = L - __expf(dnn * 0.125f - Mh) + __expf(-Mh);
    float val = (src == n) ? 0.f : d * 0.125f;
    if (lane < NTAP)
        A[(size_t)gp * NTAP + tap] = __expf(val - Mh) / Lc;
}

// ---------------- K3: output conv via per-tap MFMA, scale-after ----------------
// grid 256 = 2b x 64 rows x 2 col-halves. 256 thr = 4 waves (16q x 32o each).
__global__ __launch_bounds__(256) void k_out(
    const float* __restrict__ A, const ushort* __restrict__ VH,
    const ushort* __restrict__ Wtb, const float* __restrict__ bout,
    float* __restrict__ out)
{
    __shared__ ushort Vs[7 * 40 * 64];    // byte: kk*5120 + u*128 + swz 16B granule
    __shared__ float  Al2[NTAP][36];      // transposed attn weights
    int bid = blockIdx.x;
    int b   = bid >> 7;
    int rem = bid & 127;
    int i   = rem >> 1;
    int j0  = (rem & 1) * 32;

    int t = threadIdx.x;
    for (int g = t; g < 7 * 38 * 8; g += 256) {
        int kk = g / 304;
        int r2 = g - kk * 304;
        int u  = r2 >> 3, c8 = r2 & 7;
        int vr = iclamp(i + kk - 3);
        int vc = iclamp(j0 - 3 + u);
        bf16x8 val = *(const bf16x8*)(VH + ((size_t)((b << 12) + (vr << 6) + vc)) * 64 + c8 * 8);
        *(bf16x8*)((char*)Vs + kk * 5120 + u * 128 + ((c8 * 16) ^ ((u & 7) << 4))) = val;
    }
    for (int g = t; g < NTAP * 32; g += 256) {
        int kl = g >> 5, q = g & 31;
        Al2[kl][q] = A[((size_t)((b << 12) + (i << 6) + j0 + q)) * NTAP + kl];
    }
    __syncthreads();

    int w = t >> 6, L = t & 63;
    int q16 = (w >> 1) << 4;
    int o32 = (w & 1) << 5;
    int lrow = L & 15, lk = L >> 4;

    f32x4 acc0 = {0.f, 0.f, 0.f, 0.f};
    f32x4 acc1 = {0.f, 0.f, 0.f, 0.f};

    for (int kk = 0; kk < 7; ++kk) {
        #pragma unroll
        for (int ll = 0; ll < 7; ++ll) {
            int kl = kk * 7 + ll;
            int u = q16 + lrow + ll;
            const char* vb = (const char*)Vs + kk * 5120 + u * 128;
            int swz = (u & 7) << 4;
            bf16x8 v0 = *(const bf16x8*)(vb + ((lk * 16) ^ swz));
            bf16x8 v1 = *(const bf16x8*)(vb + ((64 + lk * 16) ^ swz));
            float4 av = *(const float4*)(&Al2[kl][q16 + lk * 4]);
            size_t wb0 = ((size_t)(kl * 64 + o32 + lrow)) * 64 + lk * 8;
            size_t wb1 = wb0 + 1024;
            bf16x8 b00 = *(const bf16x8*)(Wtb + wb0);
            bf16x8 b01 = *(const bf16x8*)(Wtb + wb0 + 32);
            bf16x8 b10 = *(const bf16x8*)(Wtb + wb1);
            bf16x8 b11 = *(const bf16x8*)(Wtb + wb1 + 32);
            f32x4 z = {0.f, 0.f, 0.f, 0.f};
            z = __builtin_amdgcn_mfma_f32_16x16x32_bf16(v0, b00, z, 0, 0, 0);
            z = __builtin_amdgcn_mfma_f32_16x16x32_bf16(v1, b01, z, 0, 0, 0);
            f32x4 y = {0.f, 0.f, 0.f, 0.f};
            y = __builtin_amdgcn_mfma_f32_16x16x32_bf16(v0, b10, y, 0, 0, 0);
            y = __builtin_amdgcn_mfma_f32_16x16x32_bf16(v1, b11, y, 0, 0, 0);
            acc0[0] = fmaf(av.x, z[0], acc0[0]); acc0[1] = fmaf(av.y, z[1], acc0[1]);
            acc0[2] = fmaf(av.z, z[2], acc0[2]); acc0[3] = fmaf(av.w, z[3], acc0[3]);
            acc1[0] = fmaf(av.x, y[0], acc1[0]); acc1[1] = fmaf(av.y, y[1], acc1[1]);
            acc1[2] = fmaf(av.z, y[2], acc1[2]); acc1[3] = fmaf(av.w, y[3], acc1[3]);
        }
    }

    int nbase = (i << 6) + j0 + q16 + lk * 4;
    {
        int o = o32 + lrow;
        float bb = bout[o];
        float4 v = make_float4(fmaxf(acc0[0] + bb, 0.f), fmaxf(acc0[1] + bb, 0.f),
                               fmaxf(acc0[2] + bb, 0.f), fmaxf(acc0[3] + bb, 0.f));
        *(float4*)(out + (((size_t)(b * 64 + o)) << 12) + nbase) = v;
    }
    {
        int o = o32 + 16 + lrow;
        float bb = bout[o];
        float4 v = make_float4(fmaxf(acc1[0] + bb, 0.f), fmaxf(acc1[1] + bb, 0.f),
                               fmaxf(acc1[2] + bb, 0.f), fmaxf(acc1[3] + bb, 0.f));
        *(float4*)(out + (((size_t)(b * 64 + o)) << 12) + nbase) = v;
    }
}

// ---------------- launch ----------------
extern "C" void kernel_launch(void* const* d_in, const int* in_sizes, int n_in,
                              void* d_out, int out_size, void* d_ws, size_t ws_size,
                              hipStream_t stream) {
    const float* x    = (const float*)d_in[0];
    const float* Wq   = (const float*)d_in[1];
    const float* bq   = (const float*)d_in[2];
    const float* Wk   = (const float*)d_in[3];
    const float* bk   = (const float*)d_in[4];
    const float* Wv   = (const float*)d_in[5];
    const float* bv   = (const float*)d_in[6];
    const float* Wp   = (const float*)d_in[7];
    const float* bp   = (const float*)d_in[8];
    const float* Wout = (const float*)d_in[9];
    const float* bout = (const float*)d_in[10];
    float* out = (float*)d_out;

    char* ws = (char*)d_ws;
    ushort* Wtb = (ushort*)(ws + WTB_OFF);
    ushort* WAh = (ushort*)(ws + WAH_OFF);
    ushort* WAl = (ushort*)(ws + WAL_OFF);
    ushort* QH  = (ushort*)(ws + QH_OFF);
    ushort* KH  = (ushort*)(ws + KH_OFF);
    ushort* VH  = (ushort*)(ws + VH_OFF);
    float*  Lp  = (float*)(ws + LP_OFF);
    float*  A   = (float*)(ws + AB_OFF);
    int*    ST  = (int*)(ws + ST_OFF);

    hipMemsetAsync(ST, 0, 16, stream);
    hipLaunchKernelGGL(k_twout,  dim3(784),  dim3(256), 0, stream, Wout, Wtb);
    hipLaunchKernelGGL(k_wsplit, dim3(192),  dim3(256), 0, stream, Wq, Wk, Wv, WAh, WAl);
    hipLaunchKernelGGL(k_qkv,    dim3(256),  dim3(256), 0, stream,
                       x, WAh, WAl, bq, bk, bv, Wp, bp, QH);
    hipLaunchKernelGGL(k_norm,   dim3(64),   dim3(128), 0, stream, QH, KH, ST);
    hipLaunchKernelGGL(k_stats,  dim3(512),  dim3(256), 0, stream, QH, KH, ST, Lp);
    hipLaunchKernelGGL(k_attn,   dim3(2048), dim3(256), 0, stream, QH, KH, Lp, ST, A);
    hipLaunchKernelGGL(k_out,    dim3(256),  dim3(256), 0, stream, A, VH, Wtb, bout, out);
}

// Round 6
// 96.091 us; speedup vs baseline: 6.1605x; 1.0643x over previous
//
#include <hip/hip_runtime.h>
#include <math.h>

// Problem constants (b=2, cin=256, h=w=64, C=64, qc=60, pd=4, OUT_K=7)
#define NTAP 49

typedef short bf16x8 __attribute__((ext_vector_type(8)));
typedef float f32x4  __attribute__((ext_vector_type(4)));

__device__ __forceinline__ float b2f(ushort u) {
    return __uint_as_float(((unsigned)u) << 16);
}
__device__ __forceinline__ ushort f2b(float f) {
    unsigned u = __float_as_uint(f);
    return (ushort)((u + 0x7FFFu + ((u >> 16) & 1u)) >> 16);
}
__device__ __forceinline__ int iclamp(int x) { return min(max(x, 0), 63); }

// ws byte offsets (total ~5.5 MB)
#define WTB_OFF 0u           // bf16 [(kl*64+o)][64c]           401408 B
#define WAH_OFF 401408u      // bf16 [192 och][256 c] hi         98304 B
#define WAL_OFF 499712u      // bf16 [192 och][256 c] lo         98304 B
#define QH_OFF  598016u      // bf16 [b*4096+n][64]            1048576 B
#define KH_OFF  1646592u
#define VH_OFF  2695168u
#define LP_OFF  3743744u     // f32 [cs*2+b][4096], cs<4        131072 B
#define AB_OFF  3874816u     // f32 [b*4096+n][49]             1605632 B
#define ST_OFF  5480448u     // 4 ints

// ---------------- K0: prep — Wout transpose, W split, ST zero ----------------
// grid 784 x 256. idx<4: zero ST; idx<49152: wsplit; idx<200704: twout.
__global__ __launch_bounds__(256) void k_prep(
    const float* __restrict__ Wout,
    const float* __restrict__ Wq, const float* __restrict__ Wk, const float* __restrict__ Wv,
    ushort* __restrict__ Wtb, ushort* __restrict__ WAh, ushort* __restrict__ WAl,
    int* __restrict__ ST)
{
    int idx = blockIdx.x * 256 + threadIdx.x;
    if (idx < 4) ST[idx] = 0;
    if (idx < 192 * 256) {
        int m = idx >> 8, c = idx & 255;
        int mat = m >> 6, o = m & 63;
        float v = 0.f;
        if (o < 60) {
            const float* Wm = (mat == 0) ? Wq : (mat == 1) ? Wk : Wv;
            v = Wm[o * 256 + c];
        }
        ushort h = f2b(v);
        WAh[idx] = h;
        WAl[idx] = f2b(v - b2f(h));
    }
    if (idx < 64 * 64 * NTAP) {
        int o   = idx / (64 * NTAP);
        int rem = idx - o * (64 * NTAP);
        int c   = rem / NTAP;
        int kl  = rem - c * NTAP;
        Wtb[(kl * 64 + o) * 64 + c] = f2b(Wout[idx]);
    }
}

// ---------------- K1: QKV projection via split-bf16 MFMA ----------------
// grid 256 = 2b x 128 pixel-tiles(32). 256 thr = 4 waves, wave = 32px x 48och.
// D = X*W^T: A-frags from swizzled LDS (x hi/lo), B-frags from L2 (WAh/WAl).
__global__ __launch_bounds__(256) void k_qkv(
    const float* __restrict__ x,
    const ushort* __restrict__ WAh, const ushort* __restrict__ WAl,
    const float* __restrict__ bq, const float* __restrict__ bk, const float* __restrict__ bv,
    const float* __restrict__ Wp, const float* __restrict__ bp,
    ushort* __restrict__ QKV)    // Q base; K=+524288, V=+1048576 (ushort elems)
{
    __shared__ ushort Xh[32 * 256];
    __shared__ ushort Xl[32 * 256];
    int bid = blockIdx.x;
    int b   = bid >> 7;
    int n0  = (bid & 127) * 32;
    int t   = threadIdx.x;

    // ---- stage x tile (32 px x 256 c) as hi/lo bf16, XOR-swizzled 16B granules ----
    {
        int p   = t & 31;
        int cg0 = t >> 5;
        #pragma unroll
        for (int it = 0; it < 4; ++it) {
            int cg = cg0 + it * 8;          // granule: c = cg*8 .. cg*8+7
            float v[8];
            #pragma unroll
            for (int e = 0; e < 8; ++e)
                v[e] = x[((size_t)(b * 256 + cg * 8 + e) << 12) + n0 + p];
            bf16x8 hi, lo;
            #pragma unroll
            for (int e = 0; e < 8; ++e) {
                ushort h = f2b(v[e]);
                hi[e] = (short)h;
                lo[e] = (short)f2b(v[e] - b2f(h));
            }
            int off = p * 256 + ((cg * 8) ^ ((p & 7) * 8));
            *(bf16x8*)(Xh + off) = hi;
            *(bf16x8*)(Xl + off) = lo;
        }
    }
    __syncthreads();

    int w = t >> 6, L = t & 63;
    int lrow = L & 15, lk = L >> 4;
    int ob = w * 48;                        // och quarter base (0,48,96,144)
    int px0 = lrow, px1 = 16 + lrow;

    f32x4 acc[2][3] = {{{0,0,0,0},{0,0,0,0},{0,0,0,0}},
                       {{0,0,0,0},{0,0,0,0},{0,0,0,0}}};

    #pragma unroll 2
    for (int c8 = 0; c8 < 8; ++c8) {
        int cidx = (c8 * 4 + lk) * 8;       // ushort offset of the 8-elem granule
        int o0 = px0 * 256 + (cidx ^ ((px0 & 7) * 8));
        int o1 = px1 * 256 + (cidx ^ ((px1 & 7) * 8));
        bf16x8 ah0 = *(const bf16x8*)(Xh + o0);
        bf16x8 al0 = *(const bf16x8*)(Xl + o0);
        bf16x8 ah1 = *(const bf16x8*)(Xh + o1);
        bf16x8 al1 = *(const bf16x8*)(Xl + o1);
        #pragma unroll
        for (int c = 0; c < 3; ++c) {
            int woff = (ob + c * 16 + lrow) * 256 + c8 * 32 + lk * 8;
            bf16x8 bh = *(const bf16x8*)(WAh + woff);
            bf16x8 bl = *(const bf16x8*)(WAl + woff);
            acc[0][c] = __builtin_amdgcn_mfma_f32_16x16x32_bf16(al0, bh, acc[0][c], 0, 0, 0);
            acc[0][c] = __builtin_amdgcn_mfma_f32_16x16x32_bf16(ah0, bl, acc[0][c], 0, 0, 0);
            acc[0][c] = __builtin_amdgcn_mfma_f32_16x16x32_bf16(ah0, bh, acc[0][c], 0, 0, 0);
            acc[1][c] = __builtin_amdgcn_mfma_f32_16x16x32_bf16(al1, bh, acc[1][c], 0, 0, 0);
            acc[1][c] = __builtin_amdgcn_mfma_f32_16x16x32_bf16(ah1, bl, acc[1][c], 0, 0, 0);
            acc[1][c] = __builtin_amdgcn_mfma_f32_16x16x32_bf16(ah1, bh, acc[1][c], 0, 0, 0);
        }
    }

    // ---- epilogue: bias or positional channel, store bf16 ----
    #pragma unroll
    for (int g = 0; g < 2; ++g) {
        #pragma unroll
        for (int c = 0; c < 3; ++c) {
            int och = ob + c * 16 + lrow;
            int mat = och >> 6;
            int o   = och & 63;
            const float* bm = (mat == 0) ? bq : (mat == 1) ? bk : bv;
            ushort* Ob = QKV + (size_t)mat * 524288;
            if (o < 60) {
                float bias = bm[o];
                #pragma unroll
                for (int e = 0; e < 4; ++e) {
                    int n = n0 + g * 16 + lk * 4 + e;
                    Ob[((size_t)((b << 12) + n)) * 64 + o] = f2b(acc[g][c][e] + bias);
                }
            } else {
                int po = o - 60;
                float w0 = Wp[2 * po], w1 = Wp[2 * po + 1], b0 = bp[po];
                #pragma unroll
                for (int e = 0; e < 4; ++e) {
                    int n = n0 + g * 16 + lk * 4 + e;
                    float fi = (float)(n >> 6), fj = (float)(n & 63);
                    Ob[((size_t)((b << 12) + n)) * 64 + o] = f2b(fmaf(w0, fi, fmaf(w1, fj, b0)));
                }
            }
        }
    }
}

// ---------------- K1b: per-batch max |q|^2, |k|^2 ----------------
__global__ __launch_bounds__(128) void k_norm(
    const ushort* __restrict__ QH, const ushort* __restrict__ KH,
    int* __restrict__ ST)
{
    int idx = blockIdx.x * 128 + threadIdx.x;   // 8192 rows
    int b = idx >> 12;
    float q2 = 0.f, k2 = 0.f;
    #pragma unroll
    for (int c8 = 0; c8 < 8; ++c8) {
        bf16x8 qv = *(const bf16x8*)(QH + (size_t)idx * 64 + c8 * 8);
        bf16x8 kv = *(const bf16x8*)(KH + (size_t)idx * 64 + c8 * 8);
        #pragma unroll
        for (int e = 0; e < 8; ++e) {
            float qf = b2f((ushort)qv[e]), kf = b2f((ushort)kv[e]);
            q2 = fmaf(qf, qf, q2);
            k2 = fmaf(kf, kf, k2);
        }
    }
    #pragma unroll
    for (int off = 1; off < 64; off <<= 1) {
        q2 = fmaxf(q2, __shfl_xor(q2, off, 64));
        k2 = fmaxf(k2, __shfl_xor(k2, off, 64));
    }
    if ((threadIdx.x & 63) == 0) {
        atomicMax(ST + b,     __float_as_int(q2));
        atomicMax(ST + 2 + b, __float_as_int(k2));
    }
}

__device__ __forceinline__ float get_mhat(const int* ST, int b) {
    float q2 = __int_as_float(ST[b]);
    float k2 = __int_as_float(ST[2 + b]);
    return 0.125f * sqrtf(q2) * sqrtf(k2) + 1.0f;
}

// ---------------- K2: softmax denominator partials via MFMA ----------------
// grid 512 = 4 keysplit x 2b x 64 rowtiles(64). 256 thr = 4 waves.
__global__ __launch_bounds__(256) void k_stats(
    const ushort* __restrict__ QH, const ushort* __restrict__ KH,
    const int* __restrict__ ST, float* __restrict__ Lp)
{
    int bid = blockIdx.x;
    int cs  = bid & 3;
    int r   = bid >> 2;
    int b   = r >> 6;
    int n0  = (r & 63) * 64;
    float Mh = get_mhat(ST, b);

    int t = threadIdx.x;
    int w = t >> 6, L = t & 63;
    int lrow = L & 15, lk = L >> 4;

    size_t qbase = ((size_t)((b << 12) + n0 + w * 16 + lrow)) * 64 + lk * 8;
    bf16x8 a0 = *(const bf16x8*)(QH + qbase);
    bf16x8 a1 = *(const bf16x8*)(QH + qbase + 32);

    float rs0 = 0.f, rs1 = 0.f, rs2 = 0.f, rs3 = 0.f;

    #pragma unroll 2
    for (int m0 = cs * 1024; m0 < cs * 1024 + 1024; m0 += 64) {
        f32x4 acc[4];
        #pragma unroll
        for (int cf = 0; cf < 4; ++cf) {
            size_t kb = ((size_t)((b << 12) + m0 + cf * 16 + lrow)) * 64 + lk * 8;
            bf16x8 b0 = *(const bf16x8*)(KH + kb);
            bf16x8 b1 = *(const bf16x8*)(KH + kb + 32);
            f32x4 z = {0.f, 0.f, 0.f, 0.f};
            z = __builtin_amdgcn_mfma_f32_16x16x32_bf16(a0, b0, z, 0, 0, 0);
            z = __builtin_amdgcn_mfma_f32_16x16x32_bf16(a1, b1, z, 0, 0, 0);
            acc[cf] = z;
        }
        #pragma unroll
        for (int cf = 0; cf < 4; ++cf) {
            rs0 += __expf(acc[cf][0] * 0.125f - Mh);
            rs1 += __expf(acc[cf][1] * 0.125f - Mh);
            rs2 += __expf(acc[cf][2] * 0.125f - Mh);
            rs3 += __expf(acc[cf][3] * 0.125f - Mh);
        }
    }
    #pragma unroll
    for (int off = 1; off < 16; off <<= 1) {
        rs0 += __shfl_xor(rs0, off, 64);
        rs1 += __shfl_xor(rs1, off, 64);
        rs2 += __shfl_xor(rs2, off, 64);
        rs3 += __shfl_xor(rs3, off, 64);
    }
    if (lrow == 0) {
        int n = n0 + w * 16 + lk * 4;
        float* dst = Lp + ((size_t)(cs * 2 + b) << 12) + n;
        dst[0] = rs0; dst[1] = rs1; dst[2] = rs2; dst[3] = rs3;
    }
}

// ---------------- K2.5: final local attention weights ----------------
__global__ __launch_bounds__(256) void k_attn(
    const ushort* __restrict__ QH, const ushort* __restrict__ KH,
    const float* __restrict__ Lp, const int* __restrict__ ST,
    float* __restrict__ A)
{
    int t    = threadIdx.x;
    int lane = t & 63;
    int gp   = blockIdx.x * 4 + (t >> 6);   // b*4096+n
    int b = gp >> 12, n = gp & 4095;
    float Mh = get_mhat(ST, b);
    float L = Lp[((size_t)(0 + b) << 12) + n] + Lp[((size_t)(2 + b) << 12) + n]
            + Lp[((size_t)(4 + b) << 12) + n] + Lp[((size_t)(6 + b) << 12) + n];

    int tap = (lane < NTAP) ? lane : 48;
    int i = n >> 6, j = n & 63;
    int kk = tap / 7, ll = tap - kk * 7;
    int src = (iclamp(i + kk - 3) << 6) + iclamp(j + ll - 3);

    const ushort* qr = QH + ((size_t)(b << 12) + n)   * 64;
    const ushort* kr = KH + ((size_t)(b << 12) + src) * 64;
    float d = 0.f;
    #pragma unroll
    for (int c8 = 0; c8 < 8; ++c8) {
        bf16x8 qv = *(const bf16x8*)(qr + c8 * 8);
        bf16x8 kv = *(const bf16x8*)(kr + c8 * 8);
        #pragma unroll
        for (int e = 0; e < 8; ++e)
            d = fmaf(b2f((ushort)qv[e]), b2f((ushort)kv[e]), d);
    }
    float dnn = __shfl(d, 24, 64);          // center tap (3,3): src == n
    float Lc  = L - __expf(dnn * 0.125f - Mh) + __expf(-Mh);
    float val = (src == n) ? 0.f : d * 0.125f;
    if (lane < NTAP)
        A[(size_t)gp * NTAP + tap] = __expf(val - Mh) / Lc;
}

// ---------------- K3: output conv via per-tap MFMA, scale-after ----------------
// grid 256 = 2b x 64 rows x 2 col-halves. 256 thr = 4 waves (16q x 32o each).
__global__ __launch_bounds__(256) void k_out(
    const float* __restrict__ A, const ushort* __restrict__ VH,
    const ushort* __restrict__ Wtb, const float* __restrict__ bout,
    float* __restrict__ out)
{
    __shared__ ushort Vs[7 * 40 * 64];    // byte: kk*5120 + u*128 + swz 16B granule
    __shared__ float  Al2[NTAP][36];      // transposed attn weights
    int bid = blockIdx.x;
    int b   = bid >> 7;
    int rem = bid & 127;
    int i   = rem >> 1;
    int j0  = (rem & 1) * 32;

    int t = threadIdx.x;
    for (int g = t; g < 7 * 38 * 8; g += 256) {
        int kk = g / 304;
        int r2 = g - kk * 304;
        int u  = r2 >> 3, c8 = r2 & 7;
        int vr = iclamp(i + kk - 3);
        int vc = iclamp(j0 - 3 + u);
        bf16x8 val = *(const bf16x8*)(VH + ((size_t)((b << 12) + (vr << 6) + vc)) * 64 + c8 * 8);
        *(bf16x8*)((char*)Vs + kk * 5120 + u * 128 + ((c8 * 16) ^ ((u & 7) << 4))) = val;
    }
    for (int g = t; g < NTAP * 32; g += 256) {
        int kl = g >> 5, q = g & 31;
        Al2[kl][q] = A[((size_t)((b << 12) + (i << 6) + j0 + q)) * NTAP + kl];
    }
    __syncthreads();

    int w = t >> 6, L = t & 63;
    int q16 = (w >> 1) << 4;
    int o32 = (w & 1) << 5;
    int lrow = L & 15, lk = L >> 4;

    f32x4 acc0 = {0.f, 0.f, 0.f, 0.f};
    f32x4 acc1 = {0.f, 0.f, 0.f, 0.f};

    for (int kk = 0; kk < 7; ++kk) {
        #pragma unroll
        for (int ll = 0; ll < 7; ++ll) {
            int kl = kk * 7 + ll;
            int u = q16 + lrow + ll;
            const char* vb = (const char*)Vs + kk * 5120 + u * 128;
            int swz = (u & 7) << 4;
            bf16x8 v0 = *(const bf16x8*)(vb + ((lk * 16) ^ swz));
            bf16x8 v1 = *(const bf16x8*)(vb + ((64 + lk * 16) ^ swz));
            float4 av = *(const float4*)(&Al2[kl][q16 + lk * 4]);
            size_t wb0 = ((size_t)(kl * 64 + o32 + lrow)) * 64 + lk * 8;
            size_t wb1 = wb0 + 1024;
            bf16x8 b00 = *(const bf16x8*)(Wtb + wb0);
            bf16x8 b01 = *(const bf16x8*)(Wtb + wb0 + 32);
            bf16x8 b10 = *(const bf16x8*)(Wtb + wb1);
            bf16x8 b11 = *(const bf16x8*)(Wtb + wb1 + 32);
            f32x4 z = {0.f, 0.f, 0.f, 0.f};
            z = __builtin_amdgcn_mfma_f32_16x16x32_bf16(v0, b00, z, 0, 0, 0);
            z = __builtin_amdgcn_mfma_f32_16x16x32_bf16(v1, b01, z, 0, 0, 0);
            f32x4 y = {0.f, 0.f, 0.f, 0.f};
            y = __builtin_amdgcn_mfma_f32_16x16x32_bf16(v0, b10, y, 0, 0, 0);
            y = __builtin_amdgcn_mfma_f32_16x16x32_bf16(v1, b11, y, 0, 0, 0);
            acc0[0] = fmaf(av.x, z[0], acc0[0]); acc0[1] = fmaf(av.y, z[1], acc0[1]);
            acc0[2] = fmaf(av.z, z[2], acc0[2]); acc0[3] = fmaf(av.w, z[3], acc0[3]);
            acc1[0] = fmaf(av.x, y[0], acc1[0]); acc1[1] = fmaf(av.y, y[1], acc1[1]);
            acc1[2] = fmaf(av.z, y[2], acc1[2]); acc1[3] = fmaf(av.w, y[3], acc1[3]);
        }
    }

    int nbase = (i << 6) + j0 + q16 + lk * 4;
    {
        int o = o32 + lrow;
        float bb = bout[o];
        float4 v = make_float4(fmaxf(acc0[0] + bb, 0.f), fmaxf(acc0[1] + bb, 0.f),
                               fmaxf(acc0[2] + bb, 0.f), fmaxf(acc0[3] + bb, 0.f));
        *(float4*)(out + (((size_t)(b * 64 + o)) << 12) + nbase) = v;
    }
    {
        int o = o32 + 16 + lrow;
        float bb = bout[o];
        float4 v = make_float4(fmaxf(acc1[0] + bb, 0.f), fmaxf(acc1[1] + bb, 0.f),
                               fmaxf(acc1[2] + bb, 0.f), fmaxf(acc1[3] + bb, 0.f));
        *(float4*)(out + (((size_t)(b * 64 + o)) << 12) + nbase) = v;
    }
}

// ---------------- launch ----------------
extern "C" void kernel_launch(void* const* d_in, const int* in_sizes, int n_in,
                              void* d_out, int out_size, void* d_ws, size_t ws_size,
                              hipStream_t stream) {
    const float* x    = (const float*)d_in[0];
    const float* Wq   = (const float*)d_in[1];
    const float* bq   = (const float*)d_in[2];
    const float* Wk   = (const float*)d_in[3];
    const float* bk   = (const float*)d_in[4];
    const float* Wv   = (const float*)d_in[5];
    const float* bv   = (const float*)d_in[6];
    const float* Wp   = (const float*)d_in[7];
    const float* bp   = (const float*)d_in[8];
    const float* Wout = (const float*)d_in[9];
    const float* bout = (const float*)d_in[10];
    float* out = (float*)d_out;

    char* ws = (char*)d_ws;
    ushort* Wtb = (ushort*)(ws + WTB_OFF);
    ushort* WAh = (ushort*)(ws + WAH_OFF);
    ushort* WAl = (ushort*)(ws + WAL_OFF);
    ushort* QH  = (ushort*)(ws + QH_OFF);
    ushort* KH  = (ushort*)(ws + KH_OFF);
    ushort* VH  = (ushort*)(ws + VH_OFF);
    float*  Lp  = (float*)(ws + LP_OFF);
    float*  A   = (float*)(ws + AB_OFF);
    int*    ST  = (int*)(ws + ST_OFF);

    hipLaunchKernelGGL(k_prep,  dim3(784),  dim3(256), 0, stream,
                       Wout, Wq, Wk, Wv, Wtb, WAh, WAl, ST);
    hipLaunchKernelGGL(k_qkv,   dim3(256),  dim3(256), 0, stream,
                       x, WAh, WAl, bq, bk, bv, Wp, bp, QH);
    hipLaunchKernelGGL(k_norm,  dim3(64),   dim3(128), 0, stream, QH, KH, ST);
    hipLaunchKernelGGL(k_stats, dim3(512),  dim3(256), 0, stream, QH, KH, ST, Lp);
    hipLaunchKernelGGL(k_attn,  dim3(2048), dim3(256), 0, stream, QH, KH, Lp, ST, A);
    hipLaunchKernelGGL(k_out,   dim3(256),  dim3(256), 0, stream, A, VH, Wtb, bout, out);
}

// Round 7
// 92.289 us; speedup vs baseline: 6.4143x; 1.0412x over previous
//
#include <hip/hip_runtime.h>
#include <math.h>

// Problem constants (b=2, cin=256, h=w=64, C=64, qc=60, pd=4, OUT_K=7)
#define NTAP 49

typedef short bf16x8 __attribute__((ext_vector_type(8)));
typedef float f32x4  __attribute__((ext_vector_type(4)));

__device__ __forceinline__ float b2f(ushort u) {
    return __uint_as_float(((unsigned)u) << 16);
}
__device__ __forceinline__ ushort f2b(float f) {
    unsigned u = __float_as_uint(f);
    return (ushort)((u + 0x7FFFu + ((u >> 16) & 1u)) >> 16);
}
__device__ __forceinline__ int iclamp(int x) { return min(max(x, 0), 63); }

#define LOG2E 1.44269504f
#define S2    (0.125f * LOG2E)

// ws byte offsets (total ~4.0 MB)
#define WTB_OFF 0u           // bf16 [(kl*64+o)][64c]           401408 B
#define WAH_OFF 401408u      // bf16 [192 och][256 c] hi         98304 B
#define WAL_OFF 499712u      // bf16 [192 och][256 c] lo         98304 B
#define QH_OFF  598016u      // bf16 [b*4096+n][64]            1048576 B
#define KH_OFF  1646592u
#define VH_OFF  2695168u
#define LP_OFF  3743744u     // f32 [cs*2+b][4096], cs<8        262144 B
#define ST_OFF  4005888u     // 4 ints

// ---------------- K0: prep — Wout transpose, W split, ST zero ----------------
__global__ __launch_bounds__(256) void k_prep(
    const float* __restrict__ Wout,
    const float* __restrict__ Wq, const float* __restrict__ Wk, const float* __restrict__ Wv,
    ushort* __restrict__ Wtb, ushort* __restrict__ WAh, ushort* __restrict__ WAl,
    int* __restrict__ ST)
{
    int idx = blockIdx.x * 256 + threadIdx.x;
    if (idx < 4) ST[idx] = 0;
    if (idx < 192 * 256) {
        int m = idx >> 8, c = idx & 255;
        int mat = m >> 6, o = m & 63;
        float v = 0.f;
        if (o < 60) {
            const float* Wm = (mat == 0) ? Wq : (mat == 1) ? Wk : Wv;
            v = Wm[o * 256 + c];
        }
        ushort h = f2b(v);
        WAh[idx] = h;
        WAl[idx] = f2b(v - b2f(h));
    }
    if (idx < 64 * 64 * NTAP) {
        int o   = idx / (64 * NTAP);
        int rem = idx - o * (64 * NTAP);
        int c   = rem / NTAP;
        int kl  = rem - c * NTAP;
        Wtb[(kl * 64 + o) * 64 + c] = f2b(Wout[idx]);
    }
}

// ---------------- K1: QKV projection via split-bf16 MFMA ----------------
// grid 256 = 2b x 128 pixel-tiles(32). 256 thr = 4 waves, wave = 32px x 48och.
__global__ __launch_bounds__(256) void k_qkv(
    const float* __restrict__ x,
    const ushort* __restrict__ WAh, const ushort* __restrict__ WAl,
    const float* __restrict__ bq, const float* __restrict__ bk, const float* __restrict__ bv,
    const float* __restrict__ Wp, const float* __restrict__ bp,
    ushort* __restrict__ QKV)    // Q base; K=+524288, V=+1048576 (ushort elems)
{
    __shared__ ushort Xh[32 * 256];
    __shared__ ushort Xl[32 * 256];
    int bid = blockIdx.x;
    int b   = bid >> 7;
    int n0  = (bid & 127) * 32;
    int t   = threadIdx.x;

    {
        int p   = t & 31;
        int cg0 = t >> 5;
        #pragma unroll
        for (int it = 0; it < 4; ++it) {
            int cg = cg0 + it * 8;
            float v[8];
            #pragma unroll
            for (int e = 0; e < 8; ++e)
                v[e] = x[((size_t)(b * 256 + cg * 8 + e) << 12) + n0 + p];
            bf16x8 hi, lo;
            #pragma unroll
            for (int e = 0; e < 8; ++e) {
                ushort h = f2b(v[e]);
                hi[e] = (short)h;
                lo[e] = (short)f2b(v[e] - b2f(h));
            }
            int off = p * 256 + ((cg * 8) ^ ((p & 7) * 8));
            *(bf16x8*)(Xh + off) = hi;
            *(bf16x8*)(Xl + off) = lo;
        }
    }
    __syncthreads();

    int w = t >> 6, L = t & 63;
    int lrow = L & 15, lk = L >> 4;
    int ob = w * 48;
    int px0 = lrow, px1 = 16 + lrow;

    f32x4 acc[2][3] = {{{0,0,0,0},{0,0,0,0},{0,0,0,0}},
                       {{0,0,0,0},{0,0,0,0},{0,0,0,0}}};

    #pragma unroll 2
    for (int c8 = 0; c8 < 8; ++c8) {
        int cidx = (c8 * 4 + lk) * 8;
        int o0 = px0 * 256 + (cidx ^ ((px0 & 7) * 8));
        int o1 = px1 * 256 + (cidx ^ ((px1 & 7) * 8));
        bf16x8 ah0 = *(const bf16x8*)(Xh + o0);
        bf16x8 al0 = *(const bf16x8*)(Xl + o0);
        bf16x8 ah1 = *(const bf16x8*)(Xh + o1);
        bf16x8 al1 = *(const bf16x8*)(Xl + o1);
        #pragma unroll
        for (int c = 0; c < 3; ++c) {
            int woff = (ob + c * 16 + lrow) * 256 + c8 * 32 + lk * 8;
            bf16x8 bh = *(const bf16x8*)(WAh + woff);
            bf16x8 bl = *(const bf16x8*)(WAl + woff);
            acc[0][c] = __builtin_amdgcn_mfma_f32_16x16x32_bf16(al0, bh, acc[0][c], 0, 0, 0);
            acc[0][c] = __builtin_amdgcn_mfma_f32_16x16x32_bf16(ah0, bl, acc[0][c], 0, 0, 0);
            acc[0][c] = __builtin_amdgcn_mfma_f32_16x16x32_bf16(ah0, bh, acc[0][c], 0, 0, 0);
            acc[1][c] = __builtin_amdgcn_mfma_f32_16x16x32_bf16(al1, bh, acc[1][c], 0, 0, 0);
            acc[1][c] = __builtin_amdgcn_mfma_f32_16x16x32_bf16(ah1, bl, acc[1][c], 0, 0, 0);
            acc[1][c] = __builtin_amdgcn_mfma_f32_16x16x32_bf16(ah1, bh, acc[1][c], 0, 0, 0);
        }
    }

    #pragma unroll
    for (int g = 0; g < 2; ++g) {
        #pragma unroll
        for (int c = 0; c < 3; ++c) {
            int och = ob + c * 16 + lrow;
            int mat = och >> 6;
            int o   = och & 63;
            const float* bm = (mat == 0) ? bq : (mat == 1) ? bk : bv;
            ushort* Ob = QKV + (size_t)mat * 524288;
            if (o < 60) {
                float bias = bm[o];
                #pragma unroll
                for (int e = 0; e < 4; ++e) {
                    int n = n0 + g * 16 + lk * 4 + e;
                    Ob[((size_t)((b << 12) + n)) * 64 + o] = f2b(acc[g][c][e] + bias);
                }
            } else {
                int po = o - 60;
                float w0 = Wp[2 * po], w1 = Wp[2 * po + 1], b0 = bp[po];
                #pragma unroll
                for (int e = 0; e < 4; ++e) {
                    int n = n0 + g * 16 + lk * 4 + e;
                    float fi = (float)(n >> 6), fj = (float)(n & 63);
                    Ob[((size_t)((b << 12) + n)) * 64 + o] = f2b(fmaf(w0, fi, fmaf(w1, fj, b0)));
                }
            }
        }
    }
}

// ---------------- K1b: per-batch max |q|^2, |k|^2 ----------------
__global__ __launch_bounds__(128) void k_norm(
    const ushort* __restrict__ QH, const ushort* __restrict__ KH,
    int* __restrict__ ST)
{
    int idx = blockIdx.x * 128 + threadIdx.x;   // 8192 rows
    int b = idx >> 12;
    float q2 = 0.f, k2 = 0.f;
    #pragma unroll
    for (int c8 = 0; c8 < 8; ++c8) {
        bf16x8 qv = *(const bf16x8*)(QH + (size_t)idx * 64 + c8 * 8);
        bf16x8 kv = *(const bf16x8*)(KH + (size_t)idx * 64 + c8 * 8);
        #pragma unroll
        for (int e = 0; e < 8; ++e) {
            float qf = b2f((ushort)qv[e]), kf = b2f((ushort)kv[e]);
            q2 = fmaf(qf, qf, q2);
            k2 = fmaf(kf, kf, k2);
        }
    }
    #pragma unroll
    for (int off = 1; off < 64; off <<= 1) {
        q2 = fmaxf(q2, __shfl_xor(q2, off, 64));
        k2 = fmaxf(k2, __shfl_xor(k2, off, 64));
    }
    if ((threadIdx.x & 63) == 0) {
        atomicMax(ST + b,     __float_as_int(q2));
        atomicMax(ST + 2 + b, __float_as_int(k2));
    }
}

__device__ __forceinline__ float get_mhat(const int* ST, int b) {
    float q2 = __int_as_float(ST[b]);
    float k2 = __int_as_float(ST[2 + b]);
    return 0.125f * sqrtf(q2) * sqrtf(k2) + 1.0f;
}

// ---------------- K2: softmax denominator partials via MFMA ----------------
// grid 1024 = 8 keysplit x 2b x 64 rowtiles(64). 256 thr = 4 waves.
__global__ __launch_bounds__(256) void k_stats(
    const ushort* __restrict__ QH, const ushort* __restrict__ KH,
    const int* __restrict__ ST, float* __restrict__ Lp)
{
    int bid = blockIdx.x;
    int cs  = bid & 7;
    int r   = bid >> 3;
    int b   = r >> 6;
    int n0  = (r & 63) * 64;
    float bse = -get_mhat(ST, b) * LOG2E;

    int t = threadIdx.x;
    int w = t >> 6, L = t & 63;
    int lrow = L & 15, lk = L >> 4;

    size_t qbase = ((size_t)((b << 12) + n0 + w * 16 + lrow)) * 64 + lk * 8;
    bf16x8 a0 = *(const bf16x8*)(QH + qbase);
    bf16x8 a1 = *(const bf16x8*)(QH + qbase + 32);

    float rs0 = 0.f, rs1 = 0.f, rs2 = 0.f, rs3 = 0.f;

    #pragma unroll 2
    for (int m0 = cs * 512; m0 < cs * 512 + 512; m0 += 64) {
        f32x4 acc[4];
        #pragma unroll
        for (int cf = 0; cf < 4; ++cf) {
            size_t kb = ((size_t)((b << 12) + m0 + cf * 16 + lrow)) * 64 + lk * 8;
            bf16x8 b0 = *(const bf16x8*)(KH + kb);
            bf16x8 b1 = *(const bf16x8*)(KH + kb + 32);
            f32x4 z = {0.f, 0.f, 0.f, 0.f};
            z = __builtin_amdgcn_mfma_f32_16x16x32_bf16(a0, b0, z, 0, 0, 0);
            z = __builtin_amdgcn_mfma_f32_16x16x32_bf16(a1, b1, z, 0, 0, 0);
            acc[cf] = z;
        }
        #pragma unroll
        for (int cf = 0; cf < 4; ++cf) {
            rs0 += exp2f(fmaf(acc[cf][0], S2, bse));
            rs1 += exp2f(fmaf(acc[cf][1], S2, bse));
            rs2 += exp2f(fmaf(acc[cf][2], S2, bse));
            rs3 += exp2f(fmaf(acc[cf][3], S2, bse));
        }
    }
    #pragma unroll
    for (int off = 1; off < 16; off <<= 1) {
        rs0 += __shfl_xor(rs0, off, 64);
        rs1 += __shfl_xor(rs1, off, 64);
        rs2 += __shfl_xor(rs2, off, 64);
        rs3 += __shfl_xor(rs3, off, 64);
    }
    if (lrow == 0) {
        int n = n0 + w * 16 + lk * 4;
        float* dst = Lp + ((size_t)(cs * 2 + b) << 12) + n;
        dst[0] = rs0; dst[1] = rs1; dst[2] = rs2; dst[3] = rs3;
    }
}

// ---------------- K3: fused local-attn + output conv ----------------
// grid 512 = 2b x 64 rows x 4 col-quarters (16 px). 256 thr = 4 waves
// (wave = 16q x 16o). Phase A: 49 local dots per pixel from L2 Q/K ->
// attn weights in LDS. Phase B: per-tap MFMA with V-halo in swizzled LDS.
__global__ __launch_bounds__(256) void k_fused(
    const ushort* __restrict__ QH, const ushort* __restrict__ KH,
    const ushort* __restrict__ VH, const ushort* __restrict__ Wtb,
    const float* __restrict__ Lp, const int* __restrict__ ST,
    const float* __restrict__ bout, float* __restrict__ out)
{
    __shared__ ushort Vs[7 * 24 * 64];   // byte: kk*3072 + u*128 + swz 16B granule
    __shared__ float  Al2[NTAP][20];     // [tap][pixel]
    __shared__ float  LcS[16];
    int bid = blockIdx.x;
    int b   = bid >> 8;
    int rem = bid & 255;
    int i   = rem >> 2;
    int j0  = (rem & 3) * 16;
    float bse = -get_mhat(ST, b) * LOG2E;

    int t = threadIdx.x;
    // ---- stage V halo: 7 rows x 22 cols x 8 granules ----
    for (int g = t; g < 7 * 22 * 8; g += 256) {
        int kk = g / 176;
        int r2 = g - kk * 176;
        int u  = r2 >> 3, c8 = r2 & 7;
        int vr = iclamp(i + kk - 3);
        int vc = iclamp(j0 - 3 + u);
        bf16x8 val = *(const bf16x8*)(VH + ((size_t)((b << 12) + (vr << 6) + vc)) * 64 + c8 * 8);
        *(bf16x8*)((char*)Vs + kk * 3072 + u * 128 + ((c8 * 16) ^ ((u & 7) << 4))) = val;
    }

    // ---- phase A: local dots (16 px x 16 thr, ~3 taps each) ----
    {
        int p = t >> 4, u = t & 15;
        int n = (i << 6) + j0 + p;
        int pi = n >> 6, pj = n & 63;     // pi == i
        const ushort* qr = QH + ((size_t)(b << 12) + n) * 64;
        bf16x8 qv[8];
        #pragma unroll
        for (int c8 = 0; c8 < 8; ++c8) qv[c8] = *(const bf16x8*)(qr + c8 * 8);

        int nt = (u == 0) ? 4 : 3;
        float d[4];
        int srcs[4];
        for (int m = 0; m < nt; ++m) {
            int tap = (m == 3) ? 48 : (u + 16 * m);
            int kk = tap / 7, ll = tap - kk * 7;
            int src = (iclamp(pi + kk - 3) << 6) + iclamp(pj + ll - 3);
            srcs[m] = src;
            const ushort* kr = KH + ((size_t)(b << 12) + src) * 64;
            float acc = 0.f;
            #pragma unroll
            for (int c8 = 0; c8 < 8; ++c8) {
                bf16x8 kv = *(const bf16x8*)(kr + c8 * 8);
                #pragma unroll
                for (int e = 0; e < 8; ++e)
                    acc = fmaf(b2f((ushort)qv[c8][e]), b2f((ushort)kv[e]), acc);
            }
            d[m] = acc;
        }
        if (u == 8) {                     // tap 24 = center (src == n always)
            float L = 0.f;
            #pragma unroll
            for (int cs = 0; cs < 8; ++cs)
                L += Lp[((size_t)(cs * 2 + b) << 12) + n];
            LcS[p] = L - exp2f(fmaf(d[1], S2, bse)) + exp2f(bse);
        }
        __syncthreads();
        float Lc = LcS[p];
        for (int m = 0; m < nt; ++m) {
            int tap = (m == 3) ? 48 : (u + 16 * m);
            float A = (srcs[m] == n) ? (exp2f(bse) / Lc)
                                     : (exp2f(fmaf(d[m], S2, bse)) / Lc);
            Al2[tap][p] = A;
        }
    }
    __syncthreads();

    // ---- phase B: per-tap MFMA, scale-after ----
    int w = t >> 6, L = t & 63;
    int lrow = L & 15, lk = L >> 4;
    int o16 = w << 4;

    f32x4 acc0 = {0.f, 0.f, 0.f, 0.f};

    for (int kk = 0; kk < 7; ++kk) {
        #pragma unroll
        for (int ll = 0; ll < 7; ++ll) {
            int kl = kk * 7 + ll;
            int u = lrow + ll;
            const char* vb = (const char*)Vs + kk * 3072 + u * 128;
            int swz = (u & 7) << 4;
            bf16x8 v0 = *(const bf16x8*)(vb + ((lk * 16) ^ swz));
            bf16x8 v1 = *(const bf16x8*)(vb + ((64 + lk * 16) ^ swz));
            float4 av = *(const float4*)(&Al2[kl][lk * 4]);
            size_t wb0 = ((size_t)(kl * 64 + o16 + lrow)) * 64 + lk * 8;
            bf16x8 b00 = *(const bf16x8*)(Wtb + wb0);
            bf16x8 b01 = *(const bf16x8*)(Wtb + wb0 + 32);
            f32x4 z = {0.f, 0.f, 0.f, 0.f};
            z = __builtin_amdgcn_mfma_f32_16x16x32_bf16(v0, b00, z, 0, 0, 0);
            z = __builtin_amdgcn_mfma_f32_16x16x32_bf16(v1, b01, z, 0, 0, 0);
            acc0[0] = fmaf(av.x, z[0], acc0[0]);
            acc0[1] = fmaf(av.y, z[1], acc0[1]);
            acc0[2] = fmaf(av.z, z[2], acc0[2]);
            acc0[3] = fmaf(av.w, z[3], acc0[3]);
        }
    }

    int o = o16 + lrow;
    int nbase = (i << 6) + j0 + lk * 4;
    float bb = bout[o];
    float4 v = make_float4(fmaxf(acc0[0] + bb, 0.f), fmaxf(acc0[1] + bb, 0.f),
                           fmaxf(acc0[2] + bb, 0.f), fmaxf(acc0[3] + bb, 0.f));
    *(float4*)(out + (((size_t)(b * 64 + o)) << 12) + nbase) = v;
}

// ---------------- launch ----------------
extern "C" void kernel_launch(void* const* d_in, const int* in_sizes, int n_in,
                              void* d_out, int out_size, void* d_ws, size_t ws_size,
                              hipStream_t stream) {
    const float* x    = (const float*)d_in[0];
    const float* Wq   = (const float*)d_in[1];
    const float* bq   = (const float*)d_in[2];
    const float* Wk   = (const float*)d_in[3];
    const float* bk   = (const float*)d_in[4];
    const float* Wv   = (const float*)d_in[5];
    const float* bv   = (const float*)d_in[6];
    const float* Wp   = (const float*)d_in[7];
    const float* bp   = (const float*)d_in[8];
    const float* Wout = (const float*)d_in[9];
    const float* bout = (const float*)d_in[10];
    float* out = (float*)d_out;

    char* ws = (char*)d_ws;
    ushort* Wtb = (ushort*)(ws + WTB_OFF);
    ushort* WAh = (ushort*)(ws + WAH_OFF);
    ushort* WAl = (ushort*)(ws + WAL_OFF);
    ushort* QH  = (ushort*)(ws + QH_OFF);
    ushort* KH  = (ushort*)(ws + KH_OFF);
    ushort* VH  = (ushort*)(ws + VH_OFF);
    float*  Lp  = (float*)(ws + LP_OFF);
    int*    ST  = (int*)(ws + ST_OFF);

    hipLaunchKernelGGL(k_prep,  dim3(784),  dim3(256), 0, stream,
                       Wout, Wq, Wk, Wv, Wtb, WAh, WAl, ST);
    hipLaunchKernelGGL(k_qkv,   dim3(256),  dim3(256), 0, stream,
                       x, WAh, WAl, bq, bk, bv, Wp, bp, QH);
    hipLaunchKernelGGL(k_norm,  dim3(64),   dim3(128), 0, stream, QH, KH, ST);
    hipLaunchKernelGGL(k_stats, dim3(1024), dim3(256), 0, stream, QH, KH, ST, Lp);
    hipLaunchKernelGGL(k_fused, dim3(512),  dim3(256), 0, stream,
                       QH, KH, VH, Wtb, Lp, ST, bout, out);
}